// Round 13
// baseline (174.001 us; speedup 1.0000x reference)
//
#include <hip/hip_runtime.h>
#include <cstdint>

typedef unsigned short u16;
typedef __bf16 bf16x8 __attribute__((ext_vector_type(8)));
typedef __bf16 bf16x2 __attribute__((ext_vector_type(2)));
typedef short s16x4 __attribute__((ext_vector_type(4)));
typedef int s32x2 __attribute__((ext_vector_type(2)));
typedef float f32x4 __attribute__((ext_vector_type(4)));

// ---- bf16 helpers (RTNE, matching XLA/ml_dtypes) ----
__device__ __forceinline__ u16 f2bf(float f) {
    unsigned u = __float_as_uint(f);
    u = (u + 0x7fffu + ((u >> 16) & 1u)) >> 16;
    return (u16)u;
}
__device__ __forceinline__ float bf2f(u16 h) {
    return __uint_as_float(((unsigned)h) << 16);
}

// async global->LDS, 16B per lane; LDS dest = wave-uniform base + lane*16
__device__ __forceinline__ void glds16(const u16* g, u16* l) {
    __builtin_amdgcn_global_load_lds(
        (const __attribute__((address_space(1))) void*)g,
        (__attribute__((address_space(3))) void*)l, 16, 0, 0);
}

// pack 4 floats -> 4 bf16 via native casts (gfx950: v_cvt_pk_bf16_f32, RTNE)
__device__ __forceinline__ s16x4 pack_bf4(float p0, float p1, float p2, float p3) {
    bf16x2 lo = {(__bf16)p0, (__bf16)p1};
    bf16x2 hi = {(__bf16)p2, (__bf16)p3};
    s32x2 pk = {__builtin_bit_cast(int, lo), __builtin_bit_cast(int, hi)};
    return __builtin_bit_cast(s16x4, pk);
}

#if __has_builtin(__builtin_amdgcn_mfma_f32_16x16x16bf16_1k)
#define MFMA16(a, b, c) __builtin_amdgcn_mfma_f32_16x16x16bf16_1k(a, b, c, 0, 0, 0)
#else
static __device__ __forceinline__ f32x4 mfma16_asm(s16x4 a, s16x4 b, f32x4 c) {
    asm("v_mfma_f32_16x16x16_bf16 %0, %1, %2, %0" : "+v"(c) : "v"(a), "v"(b));
    return c;
}
#define MFMA16(a, b, c) mfma16_asm(a, b, c)
#endif

// ============================================================================
// 1. prep: ternary-quantize both weights (8 elems/lane) + cast x to bf16.
//    GRID = 1280 quant + 2048 cast = 3328.
// ============================================================================
__global__ __launch_bounds__(256) void prep(
    const float* __restrict__ w_qkv, const float* __restrict__ w_proj,
    const float* __restrict__ x,
    u16* __restrict__ wqkv_b, u16* __restrict__ wproj_b, u16* __restrict__ xb) {
    int bid = blockIdx.x;
    if (bid < 1280) {
        const float* w; u16* o; size_t base;
        if (bid < 768) { w = w_qkv; o = wqkv_b; base = (size_t)bid * 2048; }
        else { w = w_proj; o = wproj_b; base = (size_t)(bid - 768) * 2048; }
        size_t i = base + (size_t)threadIdx.x * 8;
        float4 A = *(const float4*)(w + i);
        float4 B = *(const float4*)(w + i + 4);
        float wf[8] = {A.x, A.y, A.z, A.w, B.x, B.y, B.z, B.w};
        float wbf[8], ab[8];
        #pragma unroll
        for (int e = 0; e < 8; ++e) { wbf[e] = bf2f(f2bf(wf[e])); ab[e] = fabsf(wbf[e]); }
        float s = ((ab[0] + ab[1]) + (ab[2] + ab[3])) + ((ab[4] + ab[5]) + (ab[6] + ab[7]));
        s += __shfl_xor(s, 1);
        s += __shfl_xor(s, 2);
        s += __shfl_xor(s, 4);   // 8-lane cluster = one 64-elem group
        float scale = bf2f(f2bf(s * (1.0f / 64.0f)));
        if (scale < 1e-8f) scale = 1e-8f;
        u16 ov[8];
        #pragma unroll
        for (int e = 0; e < 8; ++e) {
            float t = bf2f(f2bf(wbf[e] / scale));
            float q = rintf(t);
            q = fminf(1.0f, fmaxf(-1.0f, q));
            float d = bf2f(f2bf(q * scale - wbf[e]));
            ov[e] = f2bf(wbf[e] + d);
        }
        *(int4*)(o + i) = *(const int4*)ov;
    } else {
        size_t i = ((size_t)(bid - 1280) * 256 + threadIdx.x) * 8;
        float4 a = *(const float4*)(x + i);
        float4 b = *(const float4*)(x + i + 4);
        u16 o[8] = {f2bf(a.x), f2bf(a.y), f2bf(a.z), f2bf(a.w),
                    f2bf(b.x), f2bf(b.y), f2bf(b.z), f2bf(b.w)};
        *(int4*)(xb + i) = *(const int4*)o;
    }
}

// ============================================================================
// 2. gemm_qkv: xb[4096x1024] @ wqkv^T with FUSED RMSNorm+RoPE+gain epilogue.
//    Tile 128M x 64N, grid 24x32 = 768 blocks = 3/CU, dbuf, one barrier/iter.
// ============================================================================
__global__ __launch_bounds__(256) void gemm_qkv(
    const u16* __restrict__ A, const u16* __restrict__ B,
    const float* __restrict__ gain,
    u16* __restrict__ Qb, u16* __restrict__ Kb, u16* __restrict__ Vt) {
    __shared__ u16 As[2][128 * 32];
    __shared__ u16 Bs[2][64 * 32];
    const int tid = threadIdx.x;
    const int lane = tid & 63, w = tid >> 6;
    const int quad = lane >> 4, l16 = lane & 15;
    const int bx = blockIdx.x, by = blockIdx.y;
    const int n0 = bx * 64, t0 = by * 128;
    const bool vblk = bx >= 20;
    const int K = 1024, nk = 32;
    const int b = by >> 4;           // batch (128-row tiles; 16 per batch)

    const int sra = w * 16 + (lane >> 2);   // A local row, +i*64
    const int srb = tid >> 2;               // B local row (0..63)
    const int sg4 = lane & 3;

    f32x4 acc[2][4];
    f32x4 zero = {0.f, 0.f, 0.f, 0.f};
    #pragma unroll
    for (int i = 0; i < 2; ++i)
        #pragma unroll
        for (int j = 0; j < 4; ++j) acc[i][j] = zero;

    int aoff[2], boff[4];
    #pragma unroll
    for (int mi = 0; mi < 2; ++mi) {
        int r = w * 32 + mi * 16 + l16;
        aoff[mi] = r * 32 + (quad ^ ((r >> 1) & 3)) * 8;
    }
    #pragma unroll
    for (int ni = 0; ni < 4; ++ni) {
        int rb = ni * 16 + l16;
        boff[ni] = rb * 32 + (quad ^ ((rb >> 1) & 3)) * 8;
    }

    #pragma unroll
    for (int i = 0; i < 2; ++i) {
        int r = sra + i * 64;
        int g = sg4 ^ ((r >> 1) & 3);
        glds16(A + (size_t)(t0 + r) * K + g * 8, &As[0][0] + (w * 16 + i * 64) * 32 + lane * 8);
    }
    {
        int g = sg4 ^ ((srb >> 1) & 3);
        glds16(B + (size_t)(n0 + srb) * K + g * 8, &Bs[0][0] + w * 512 + lane * 8);
    }
    __syncthreads();

    for (int kt = 0; kt < nk; ++kt) {
        if (kt + 1 < nk) {
            int k0 = (kt + 1) * 32, bi = (kt + 1) & 1;
            #pragma unroll
            for (int i = 0; i < 2; ++i) {
                int r = sra + i * 64;
                int g = sg4 ^ ((r >> 1) & 3);
                glds16(A + (size_t)(t0 + r) * K + k0 + g * 8, &As[bi][0] + (w * 16 + i * 64) * 32 + lane * 8);
            }
            int g = sg4 ^ ((srb >> 1) & 3);
            glds16(B + (size_t)(n0 + srb) * K + k0 + g * 8, &Bs[bi][0] + w * 512 + lane * 8);
        }
        const u16* as = &As[kt & 1][0];
        const u16* bs = &Bs[kt & 1][0];
        bf16x8 af[2], bfr[4];
        #pragma unroll
        for (int mi = 0; mi < 2; ++mi) af[mi]  = *(const bf16x8*)(as + aoff[mi]);
        #pragma unroll
        for (int ni = 0; ni < 4; ++ni) bfr[ni] = *(const bf16x8*)(bs + boff[ni]);
        if (!vblk) {
            #pragma unroll
            for (int mi = 0; mi < 2; ++mi)
                #pragma unroll
                for (int ni = 0; ni < 4; ++ni)
                    acc[mi][ni] = __builtin_amdgcn_mfma_f32_16x16x32_bf16(af[mi], bfr[ni], acc[mi][ni], 0, 0, 0);
        } else {
            #pragma unroll
            for (int mi = 0; mi < 2; ++mi)
                #pragma unroll
                for (int ni = 0; ni < 4; ++ni)
                    acc[mi][ni] = __builtin_amdgcn_mfma_f32_16x16x32_bf16(bfr[ni], af[mi], acc[mi][ni], 0, 0, 0);
        }
        __syncthreads();
    }

    if (vblk) {
        const int kv = bx - 20;
        u16* vbase = Vt + (size_t)(b * 4 + kv) * 64 * 2048;
        const int si = (t0 + w * 32 + l16) & 2047;
        #pragma unroll
        for (int mi = 0; mi < 2; ++mi)
            #pragma unroll
            for (int ni = 0; ni < 4; ++ni) {
                int d = ni * 16 + quad * 4;
                #pragma unroll
                for (int r = 0; r < 4; ++r)
                    vbase[(size_t)(d + r) * 2048 + si + mi * 16] = f2bf(acc[mi][ni][r]);
            }
    } else {
        const bool isQ = bx < 16;
        const float sc = 0.18033688011112042f;
        const float g = isQ ? gain[bx] * sc : 1.0f;
        u16* base = isQ ? (Qb + (size_t)(b * 16 + bx) * 2048 * 64)
                        : (Kb + (size_t)(b * 4 + (bx - 16)) * 2048 * 64);
        const float eps = 1.1920929e-7f;
        const float invf0 = (float)(1.0 / pow(10000.0, (double)l16 / 32.0));
        const float invf1 = (float)(1.0 / pow(10000.0, (double)(l16 + 16) / 32.0));
        #pragma unroll
        for (int mi = 0; mi < 2; ++mi) {
            #pragma unroll
            for (int r = 0; r < 4; ++r) {
                float v0 = acc[mi][0][r], v1 = acc[mi][1][r];
                float v2 = acc[mi][2][r], v3 = acc[mi][3][r];
                float ssq = (v0 * v0 + v1 * v1) + (v2 * v2 + v3 * v3);
                #pragma unroll
                for (int m = 1; m < 16; m <<= 1) ssq += __shfl_xor(ssq, m);
                float rn = 1.0f / sqrtf(ssq * (1.0f / 64.0f) + eps);
                int si = (t0 + w * 32 + mi * 16 + quad * 4 + r) & 2047;
                float a0 = (float)si * invf0, a1 = (float)si * invf1;
                float c0 = __cosf(a0), s0 = __sinf(a0);
                float c1 = __cosf(a1), s1 = __sinf(a1);
                float x1a = v0 * rn, x2a = v2 * rn;
                float x1b = v1 * rn, x2b = v3 * rn;
                u16* row = base + (size_t)si * 64;
                row[l16]      = f2bf((x1a * c0 + x2a * s0) * g);
                row[l16 + 32] = f2bf((x2a * c0 - x1a * s0) * g);
                row[l16 + 16] = f2bf((x1b * c1 + x2b * s1) * g);
                row[l16 + 48] = f2bf((x2b * c1 - x1b * s1) * g);
            }
        }
    }
}

// ============================================================================
// 3. GEMM (proj): C[M,N] fp32 = A[M,K]bf16 @ B[N,K]^T. 128M x 64N, dbuf,
//    one barrier/iter.
// ============================================================================
__global__ __launch_bounds__(256) void gemm_bt(
    const u16* __restrict__ A, const u16* __restrict__ B,
    float* __restrict__ C, int M, int N, int K) {
    __shared__ u16 As[2][128 * 32];
    __shared__ u16 Bs[2][64 * 32];
    const int tid = threadIdx.x;
    const int lane = tid & 63, w = tid >> 6;
    const int quad = lane >> 4, l16 = lane & 15;
    const int m0 = blockIdx.y * 128, n0 = blockIdx.x * 64;
    const int wm = (w >> 1) * 64, wn = (w & 1) * 32;

    const int sra = w * 16 + (lane >> 2);
    const int srb = tid >> 2;
    const int sg4 = lane & 3;

    f32x4 acc[4][2];
    f32x4 zero = {0.f, 0.f, 0.f, 0.f};
    #pragma unroll
    for (int i = 0; i < 4; ++i) { acc[i][0] = zero; acc[i][1] = zero; }

    int aoff[4], boff[2];
    #pragma unroll
    for (int mi = 0; mi < 4; ++mi) {
        int r = wm + mi * 16 + l16;
        aoff[mi] = r * 32 + (quad ^ ((r >> 1) & 3)) * 8;
    }
    #pragma unroll
    for (int ni = 0; ni < 2; ++ni) {
        int r = wn + ni * 16 + l16;
        boff[ni] = r * 32 + (quad ^ ((r >> 1) & 3)) * 8;
    }

    const int nk = K >> 5;
    #pragma unroll
    for (int i = 0; i < 2; ++i) {
        int r = sra + i * 64;
        int g = sg4 ^ ((r >> 1) & 3);
        glds16(A + (size_t)(m0 + r) * K + g * 8, &As[0][0] + (w * 16 + i * 64) * 32 + lane * 8);
    }
    {
        int g = sg4 ^ ((srb >> 1) & 3);
        glds16(B + (size_t)(n0 + srb) * K + g * 8, &Bs[0][0] + w * 512 + lane * 8);
    }
    __syncthreads();

    for (int kt = 0; kt < nk; ++kt) {
        if (kt + 1 < nk) {
            int k0 = (kt + 1) * 32, bi = (kt + 1) & 1;
            #pragma unroll
            for (int i = 0; i < 2; ++i) {
                int r = sra + i * 64;
                int g = sg4 ^ ((r >> 1) & 3);
                glds16(A + (size_t)(m0 + r) * K + k0 + g * 8, &As[bi][0] + (w * 16 + i * 64) * 32 + lane * 8);
            }
            int g = sg4 ^ ((srb >> 1) & 3);
            glds16(B + (size_t)(n0 + srb) * K + k0 + g * 8, &Bs[bi][0] + w * 512 + lane * 8);
        }
        const u16* as = &As[kt & 1][0];
        const u16* bs = &Bs[kt & 1][0];
        bf16x8 af[4], bfr[2];
        #pragma unroll
        for (int mi = 0; mi < 4; ++mi) af[mi]  = *(const bf16x8*)(as + aoff[mi]);
        #pragma unroll
        for (int ni = 0; ni < 2; ++ni) bfr[ni] = *(const bf16x8*)(bs + boff[ni]);
        #pragma unroll
        for (int mi = 0; mi < 4; ++mi)
            #pragma unroll
            for (int ni = 0; ni < 2; ++ni)
                acc[mi][ni] = __builtin_amdgcn_mfma_f32_16x16x32_bf16(af[mi], bfr[ni], acc[mi][ni], 0, 0, 0);
        __syncthreads();
    }
    #pragma unroll
    for (int mi = 0; mi < 4; ++mi)
        #pragma unroll
        for (int ni = 0; ni < 2; ++ni) {
            int rg = m0 + wm + mi * 16 + quad * 4;
            int cg = n0 + wn + ni * 16 + l16;
            float* cp = C + (size_t)rg * N + cg;
            #pragma unroll
            for (int r = 0; r < 4; ++r) cp[(size_t)r * N] = acc[mi][ni][r];
        }
}

// ============================================================================
// 4. Flash attention (R9 structure — verified best; attn ~44us).
//    256 thr / 4 waves; each wave owns 32 Q-rows (two 16-bands), K/V LDS
//    fragments feed both bands. Q-tile 128, KV tile 64, dbuf LDS 32KB.
//    Grid 32 x 40 LPT chunks (1..8 tiles), Opart bf16.
//    launch_bounds (256,4): kernel needs ~60 VGPR; any tighter cap (R11's
//    ",5" -> 48 VGPR) or extra live state (R8's PV pipeline) spills to
//    scratch and regresses 1.3-1.8x. Do not tighten.
//    NEW vs R12: full-chunk rows write y in BF16 (was f32) — halves the
//    y round-trip (~4.2MB saved); same precision class as the already-
//    accepted bf16 Opart path.
// ============================================================================
__global__ __launch_bounds__(256, 4) void attn(
    const u16* __restrict__ Qb, const u16* __restrict__ Kb,
    const u16* __restrict__ Vt, const float* __restrict__ gain,
    u16* __restrict__ y, u16* __restrict__ Opart, float* __restrict__ ml) {
    __shared__ u16 Ks[2][4096];
    __shared__ u16 Vs[2][4096];
    const int hb = blockIdx.x;
    const int h = hb & 15, b = hb >> 4, kvh = h >> 2;
    const int yid = 39 - blockIdx.y;   // LPT: physical y=0 -> biggest chunk
    // chunk tables: bq (0..15), T=2bq+2 tiles, nch=ceil(T/8)
    const int nch_t[16] = {1,1,1,1,2,2,2,2,3,3,3,3,4,4,4,4};
    const int cst_t[16] = {0,1,2,3,4,6,8,10,12,15,18,21,24,28,32,36};
    int bq = 0;
    #pragma unroll
    for (int i = 1; i < 16; ++i) if (yid >= cst_t[i]) bq = i;
    const int nc = nch_t[bq], ch = yid - cst_t[bq];
    const int T = 2 * bq + 2;
    const int c0 = ch * T / nc;
    const int nj = (ch + 1) * T / nc - c0;
    const bool partial = nc > 1;
    const int q0 = bq * 128;

    const int tid = threadIdx.x, lane = tid & 63, w = tid >> 6;  // w 0..3
    const int quad = lane >> 4, l16 = lane & 15;
    const float nM = -(12.0f * fabsf(gain[h]) + 1.0f);
    const f32x4 minit = {nM, nM, nM, nM};

    const u16* Qg = Qb + ((size_t)(b * 16 + h) * 2048 + q0) * 64;
    const u16* Kg = Kb + (size_t)(b * 4 + kvh) * 2048 * 64;
    const u16* Vg = Vt + (size_t)(b * 4 + kvh) * 64 * 2048;

    // two bands per wave: q rows w*32+l16 and +16
    const int qr0 = w * 32 + l16;
    const bf16x8 qa00 = *(const bf16x8*)(Qg + (size_t)qr0 * 64 + quad * 8);
    const bf16x8 qa01 = *(const bf16x8*)(Qg + (size_t)qr0 * 64 + 32 + quad * 8);
    const bf16x8 qa10 = *(const bf16x8*)(Qg + (size_t)(qr0 + 16) * 64 + quad * 8);
    const bf16x8 qa11 = *(const bf16x8*)(Qg + (size_t)(qr0 + 16) * 64 + 32 + quad * 8);

    // staging: 256 thr x 16B x 2 passes per 8KB tile
    const int sr = tid >> 3;                 // 0..31
    const int sg = (tid & 7) ^ (sr & 7);     // XOR swizzle (same for sr+32)
    const int so = tid * 8;                  // u16 offset in LDS

    {
        int c = (c0 + nj - 1) * 64, bi = (nj - 1) & 1;
        glds16(Kg + (size_t)(c + sr) * 64 + sg * 8,        &Ks[bi][0] + so);
        glds16(Kg + (size_t)(c + sr + 32) * 64 + sg * 8,   &Ks[bi][0] + so + 2048);
        glds16(Vg + (size_t)sr * 2048 + c + sg * 8,        &Vs[bi][0] + so);
        glds16(Vg + (size_t)(sr + 32) * 2048 + c + sg * 8, &Vs[bi][0] + so + 2048);
    }
    __syncthreads();

    f32x4 o0[4], o1[4];
    f32x4 zero = {0.f, 0.f, 0.f, 0.f};
    #pragma unroll
    for (int t = 0; t < 4; ++t) { o0[t] = zero; o1[t] = zero; }
    float l0 = 0.f, l1 = 0.f;

    for (int jj = nj - 1; jj >= 0; --jj) {
        if (jj > 0) {
            int c = (c0 + jj - 1) * 64, bi = (jj - 1) & 1;
            glds16(Kg + (size_t)(c + sr) * 64 + sg * 8,        &Ks[bi][0] + so);
            glds16(Kg + (size_t)(c + sr + 32) * 64 + sg * 8,   &Ks[bi][0] + so + 2048);
            glds16(Vg + (size_t)sr * 2048 + c + sg * 8,        &Vs[bi][0] + so);
            glds16(Vg + (size_t)(sr + 32) * 2048 + c + sg * 8, &Vs[bi][0] + so + 2048);
        }
        const u16* Kt = &Ks[jj & 1][0];
        const u16* Vl = &Vs[jj & 1][0];
        const int jg = c0 + jj;
        const int d0 = 8 * bq + 2 * w - 4 * jg;   // band0 position (16-units)
        const int d1 = d0 + 1;
        if (d1 >= 0) {
            const int tm0 = d0 < 3 ? d0 : 3;       // may be -1 (band0 idle)
            const int tm1 = d1 < 3 ? d1 : 3;
            s16x4 pf0[4], pf1[4];
            float rs0 = 0.f, rs1 = 0.f;
            __builtin_amdgcn_s_setprio(1);
            #pragma unroll
            for (int t = 0; t < 4; ++t) {
                if (t <= tm1) {
                    int rk = t * 16 + l16;
                    bf16x8 kb0 = *(const bf16x8*)(Kt + rk * 64 + ((quad ^ (rk & 7)) * 8));
                    bf16x8 kb1 = *(const bf16x8*)(Kt + rk * 64 + (((quad + 4) ^ (rk & 7)) * 8));
                    if (t <= tm0) {
                        f32x4 s = __builtin_amdgcn_mfma_f32_16x16x32_bf16(kb0, qa00, minit, 0, 0, 0);
                        s = __builtin_amdgcn_mfma_f32_16x16x32_bf16(kb1, qa01, s, 0, 0, 0);
                        if (t == d0) {
                            #pragma unroll
                            for (int r = 0; r < 4; ++r)
                                if (quad * 4 + r > l16) s[r] = -1e30f;
                        }
                        float p0 = __builtin_amdgcn_exp2f(s[0]);
                        float p1 = __builtin_amdgcn_exp2f(s[1]);
                        float p2 = __builtin_amdgcn_exp2f(s[2]);
                        float p3 = __builtin_amdgcn_exp2f(s[3]);
                        rs0 += (p0 + p1) + (p2 + p3);
                        pf0[t] = pack_bf4(p0, p1, p2, p3);
                    }
                    {
                        f32x4 s = __builtin_amdgcn_mfma_f32_16x16x32_bf16(kb0, qa10, minit, 0, 0, 0);
                        s = __builtin_amdgcn_mfma_f32_16x16x32_bf16(kb1, qa11, s, 0, 0, 0);
                        if (t == d1) {
                            #pragma unroll
                            for (int r = 0; r < 4; ++r)
                                if (quad * 4 + r > l16) s[r] = -1e30f;
                        }
                        float p0 = __builtin_amdgcn_exp2f(s[0]);
                        float p1 = __builtin_amdgcn_exp2f(s[1]);
                        float p2 = __builtin_amdgcn_exp2f(s[2]);
                        float p3 = __builtin_amdgcn_exp2f(s[3]);
                        rs1 += (p0 + p1) + (p2 + p3);
                        pf1[t] = pack_bf4(p0, p1, p2, p3);
                    }
                }
            }
            l0 += rs0; l1 += rs1;
            #pragma unroll
            for (int dt = 0; dt < 4; ++dt) {
                int rv = dt * 16 + l16;
                #pragma unroll
                for (int kt = 0; kt < 4; ++kt) {
                    if (kt <= tm1) {
                        int gv = 2 * kt + (quad >> 1);
                        s16x4 va = *(const s16x4*)(Vl + rv * 64 + ((gv ^ (rv & 7)) * 8) + (quad & 1) * 4);
                        if (kt <= tm0) o0[dt] = MFMA16(va, pf0[kt], o0[dt]);
                        o1[dt] = MFMA16(va, pf1[kt], o1[dt]);
                    }
                }
            }
            __builtin_amdgcn_s_setprio(0);
        }
        __syncthreads();
    }

    // finish row-sums: quads hold disjoint k-slices
    l0 += __shfl_xor(l0, 16);
    l0 += __shfl_xor(l0, 32);
    l1 += __shfl_xor(l1, 16);
    l1 += __shfl_xor(l1, 32);

    const int q = w * 32 + l16;
    if (!partial) {
        const float inv0 = 1.0f / l0, inv1 = 1.0f / l1;
        const size_t row0 = (size_t)b * 2048 + q0 + q;
        u16* yp0 = y + row0 * 1024 + h * 64 + quad * 4;
        u16* yp1 = y + (row0 + 16) * 1024 + h * 64 + quad * 4;
        #pragma unroll
        for (int dt = 0; dt < 4; ++dt) {
            f32x4 a = o0[dt] * inv0;
            *(s16x4*)(yp0 + dt * 16) = pack_bf4(a[0], a[1], a[2], a[3]);
            f32x4 c = o1[dt] * inv1;
            *(s16x4*)(yp1 + dt * 16) = pack_bf4(c[0], c[1], c[2], c[3]);
        }
    } else {
        const int slot = hb * 36 + (yid - 4);
        u16* Op = Opart + (size_t)slot * 8192;
        #pragma unroll
        for (int dt = 0; dt < 4; ++dt) {
            *(s16x4*)(Op + q * 64 + dt * 16 + quad * 4) =
                pack_bf4(o0[dt][0], o0[dt][1], o0[dt][2], o0[dt][3]);
            *(s16x4*)(Op + (q + 16) * 64 + dt * 16 + quad * 4) =
                pack_bf4(o1[dt][0], o1[dt][1], o1[dt][2], o1[dt][3]);
        }
        if (quad == 0) {
            ml[slot * 128 + q] = l0;
            ml[slot * 128 + q + 16] = l1;
        }
    }
}

// ============================================================================
// 5. rmsnorm_merge: rows s<512 read y (BF16); rows s>=512 combine split-K
//    partials (nch[bq] chunks, 2..4; Opart BF16, l fp32, accumulate fp32).
// ============================================================================
__global__ __launch_bounds__(256) void rmsnorm_merge(
    const u16* __restrict__ y, const u16* __restrict__ Opart,
    const float* __restrict__ ml, u16* __restrict__ yb) {
    __shared__ float red[4];
    const int row = blockIdx.x, tid = threadIdx.x;
    const int b = row >> 11, s = row & 2047;
    float4 v;
    if (s < 512) {
        s16x4 pv = *(const s16x4*)(y + (size_t)row * 1024 + tid * 4);
        v.x = bf2f((u16)pv[0]); v.y = bf2f((u16)pv[1]);
        v.z = bf2f((u16)pv[2]); v.w = bf2f((u16)pv[3]);
    } else {
        const int nch_t[16] = {1,1,1,1,2,2,2,2,3,3,3,3,4,4,4,4};
        const int cst_t[16] = {0,1,2,3,4,6,8,10,12,15,18,21,24,28,32,36};
        const int bq = s >> 7, q = s & 127;
        const int e = tid * 4, h = e >> 6, dh = e & 63;
        const int n = nch_t[bq];
        const int slot0 = (b * 16 + h) * 36 + (cst_t[bq] - 4);
        float l = 0.f;
        f32x4 xa = {0.f, 0.f, 0.f, 0.f};
        const u16* P = Opart + (size_t)slot0 * 8192 + q * 64 + dh;
        for (int c = 0; c < n; ++c) {
            l += ml[(size_t)(slot0 + c) * 128 + q];
            s16x4 pv = *(const s16x4*)(P + (size_t)c * 8192);
            f32x4 pf = {bf2f((u16)pv[0]), bf2f((u16)pv[1]),
                        bf2f((u16)pv[2]), bf2f((u16)pv[3])};
            xa += pf;
        }
        float inv = 1.0f / l;
        v.x = xa[0] * inv; v.y = xa[1] * inv; v.z = xa[2] * inv; v.w = xa[3] * inv;
    }
    float ss = v.x * v.x + v.y * v.y + v.z * v.z + v.w * v.w;
    #pragma unroll
    for (int m = 1; m < 64; m <<= 1) ss += __shfl_xor(ss, m);
    if ((tid & 63) == 0) red[tid >> 6] = ss;
    __syncthreads();
    float tot = red[0] + red[1] + red[2] + red[3];
    float rn = 1.0f / sqrtf(tot * (1.0f / 1024.0f) + 1.1920929e-7f);
    u16 o[4] = {f2bf(v.x * rn), f2bf(v.y * rn), f2bf(v.z * rn), f2bf(v.w * rn)};
    *(uint2*)(yb + (size_t)row * 1024 + tid * 4) = *(const uint2*)o;
}

// ============================================================================
// launch — workspace (peak ~51 MB; ws is 256 MiB per harness poison-fill):
//   [0,      2.10M)  wproj_b  (prep -> gemm2)
//   [2.10M, 10.49M)  xb (prep -> gemm_qkv); then y BF16 @2.10M..10.49M
//                    (attn -> rms; xb dead by attn time)
//   [10.49M,13.63M)  wqkv_b (prep -> gemm_qkv)
//   [18.87M,27.26M)  Qb (gemm_qkv -> attn); then yb (rms -> gemm2)
//   [27.26M,29.36M)  Kb   [29.36M,31.46M) Vt
//   [31.46M,50.33M)  Opart (attn -> rms; 32 hb x 36 slots x 8192 BF16)
//   [50.33M,50.92M)  ml (1152 slots x 128 f32)
// ============================================================================
extern "C" void kernel_launch(void* const* d_in, const int* in_sizes, int n_in,
                              void* d_out, int out_size, void* d_ws, size_t ws_size,
                              hipStream_t stream) {
    const float* x      = (const float*)d_in[0];
    const float* w_qkv  = (const float*)d_in[1];
    const float* w_proj = (const float*)d_in[2];
    const float* q_gain = (const float*)d_in[3];
    float* out = (float*)d_out;
    char* ws = (char*)d_ws;

    u16*   wproj_b = (u16*)(ws);
    u16*   xb      = (u16*)(ws + 2097152);
    u16*   y       = (u16*)(ws + 2097152);
    u16*   wqkv_b  = (u16*)(ws + 10485760);
    u16*   Qb      = (u16*)(ws + 18874368);
    u16*   yb      = (u16*)(ws + 18874368);
    u16*   Kb      = (u16*)(ws + 27262976);
    u16*   Vt      = (u16*)(ws + 29360128);
    u16*   Opart   = (u16*)(ws + 31457280);
    float* mlb     = (float*)(ws + 50331648);

    prep<<<3328, 256, 0, stream>>>(w_qkv, w_proj, x, wqkv_b, wproj_b, xb);
    gemm_qkv<<<dim3(24, 32), 256, 0, stream>>>(xb, wqkv_b, q_gain, Qb, Kb, Vt);
    attn<<<dim3(32, 40), 256, 0, stream>>>(Qb, Kb, Vt, q_gain, y, Opart, mlb);
    rmsnorm_merge<<<4096, 256, 0, stream>>>(y, Opart, mlb, yb);
    gemm_bt<<<dim3(16, 32), 256, 0, stream>>>(yb, wproj_b, out, 4096, 1024, 1024);
}

// Round 14
// 169.535 us; speedup vs baseline: 1.0263x; 1.0263x over previous
//
#include <hip/hip_runtime.h>
#include <cstdint>

typedef unsigned short u16;
typedef __bf16 bf16x8 __attribute__((ext_vector_type(8)));
typedef __bf16 bf16x2 __attribute__((ext_vector_type(2)));
typedef short s16x4 __attribute__((ext_vector_type(4)));
typedef int s32x2 __attribute__((ext_vector_type(2)));
typedef float f32x4 __attribute__((ext_vector_type(4)));

// ---- bf16 helpers (RTNE, matching XLA/ml_dtypes) ----
__device__ __forceinline__ u16 f2bf(float f) {
    unsigned u = __float_as_uint(f);
    u = (u + 0x7fffu + ((u >> 16) & 1u)) >> 16;
    return (u16)u;
}
__device__ __forceinline__ float bf2f(u16 h) {
    return __uint_as_float(((unsigned)h) << 16);
}

// async global->LDS, 16B per lane; LDS dest = wave-uniform base + lane*16
__device__ __forceinline__ void glds16(const u16* g, u16* l) {
    __builtin_amdgcn_global_load_lds(
        (const __attribute__((address_space(1))) void*)g,
        (__attribute__((address_space(3))) void*)l, 16, 0, 0);
}

// pack 4 floats -> 4 bf16 via native casts (gfx950: v_cvt_pk_bf16_f32, RTNE)
__device__ __forceinline__ s16x4 pack_bf4(float p0, float p1, float p2, float p3) {
    bf16x2 lo = {(__bf16)p0, (__bf16)p1};
    bf16x2 hi = {(__bf16)p2, (__bf16)p3};
    s32x2 pk = {__builtin_bit_cast(int, lo), __builtin_bit_cast(int, hi)};
    return __builtin_bit_cast(s16x4, pk);
}

#if __has_builtin(__builtin_amdgcn_mfma_f32_16x16x16bf16_1k)
#define MFMA16(a, b, c) __builtin_amdgcn_mfma_f32_16x16x16bf16_1k(a, b, c, 0, 0, 0)
#else
static __device__ __forceinline__ f32x4 mfma16_asm(s16x4 a, s16x4 b, f32x4 c) {
    asm("v_mfma_f32_16x16x16_bf16 %0, %1, %2, %0" : "+v"(c) : "v"(a), "v"(b));
    return c;
}
#define MFMA16(a, b, c) mfma16_asm(a, b, c)
#endif

// ============================================================================
// 1. prep: ternary-quantize both weights (8 elems/lane) + cast x to bf16.
//    GRID = 1280 quant + 2048 cast = 3328.
// ============================================================================
__global__ __launch_bounds__(256) void prep(
    const float* __restrict__ w_qkv, const float* __restrict__ w_proj,
    const float* __restrict__ x,
    u16* __restrict__ wqkv_b, u16* __restrict__ wproj_b, u16* __restrict__ xb) {
    int bid = blockIdx.x;
    if (bid < 1280) {
        const float* w; u16* o; size_t base;
        if (bid < 768) { w = w_qkv; o = wqkv_b; base = (size_t)bid * 2048; }
        else { w = w_proj; o = wproj_b; base = (size_t)(bid - 768) * 2048; }
        size_t i = base + (size_t)threadIdx.x * 8;
        float4 A = *(const float4*)(w + i);
        float4 B = *(const float4*)(w + i + 4);
        float wf[8] = {A.x, A.y, A.z, A.w, B.x, B.y, B.z, B.w};
        float wbf[8], ab[8];
        #pragma unroll
        for (int e = 0; e < 8; ++e) { wbf[e] = bf2f(f2bf(wf[e])); ab[e] = fabsf(wbf[e]); }
        float s = ((ab[0] + ab[1]) + (ab[2] + ab[3])) + ((ab[4] + ab[5]) + (ab[6] + ab[7]));
        s += __shfl_xor(s, 1);
        s += __shfl_xor(s, 2);
        s += __shfl_xor(s, 4);   // 8-lane cluster = one 64-elem group
        float scale = bf2f(f2bf(s * (1.0f / 64.0f)));
        if (scale < 1e-8f) scale = 1e-8f;
        u16 ov[8];
        #pragma unroll
        for (int e = 0; e < 8; ++e) {
            float t = bf2f(f2bf(wbf[e] / scale));
            float q = rintf(t);
            q = fminf(1.0f, fmaxf(-1.0f, q));
            float d = bf2f(f2bf(q * scale - wbf[e]));
            ov[e] = f2bf(wbf[e] + d);
        }
        *(int4*)(o + i) = *(const int4*)ov;
    } else {
        size_t i = ((size_t)(bid - 1280) * 256 + threadIdx.x) * 8;
        float4 a = *(const float4*)(x + i);
        float4 b = *(const float4*)(x + i + 4);
        u16 o[8] = {f2bf(a.x), f2bf(a.y), f2bf(a.z), f2bf(a.w),
                    f2bf(b.x), f2bf(b.y), f2bf(b.z), f2bf(b.w)};
        *(int4*)(xb + i) = *(const int4*)o;
    }
}

// ============================================================================
// 2. gemm_qkv: xb[4096x1024] @ wqkv^T with FUSED RMSNorm+RoPE+gain epilogue.
//    Tile 128M x 64N, grid 24x32 = 768 blocks = 3/CU.
//    NEW (R14): BK=64 — each LDS buffer holds TWO 32-col sub-tiles (same
//    swizzled 128x32 / 64x32 layouts, stored sequentially), and each barrier
//    region runs 2 MFMA sub-steps. Barriers/block 32 -> 16; per-barrier MFMA
//    doubles. Measured R13: MfmaUtil 9.6%, VALU 13.7%, HBM 12.7% — the
//    vmcnt(0)-drain-per-32-K-step dominated. LDS 24 -> 48KB (3 blocks/CU,
//    grid-limited to 3 anyway).
// ============================================================================
__global__ __launch_bounds__(256) void gemm_qkv(
    const u16* __restrict__ A, const u16* __restrict__ B,
    const float* __restrict__ gain,
    u16* __restrict__ Qb, u16* __restrict__ Kb, u16* __restrict__ Vt) {
    __shared__ u16 As[2 * 8192];   // 2 bufs x (2 sub x 128x32)
    __shared__ u16 Bs[2 * 4096];   // 2 bufs x (2 sub x 64x32)
    const int tid = threadIdx.x;
    const int lane = tid & 63, w = tid >> 6;
    const int quad = lane >> 4, l16 = lane & 15;
    const int bx = blockIdx.x, by = blockIdx.y;
    const int n0 = bx * 64, t0 = by * 128;
    const bool vblk = bx >= 20;
    const int K = 1024, nk = 16;   // 16 K-steps of 64
    const int b = by >> 4;           // batch (128-row tiles; 16 per batch)

    const int sra = w * 16 + (lane >> 2);   // A local row, +i*64
    const int srb = tid >> 2;               // B local row (0..63)
    const int sg4 = lane & 3;
    const int adst = (w * 16) * 32 + lane * 8;   // + i*64*32, + sub*4096
    const int bdst = w * 512 + lane * 8;         // + sub*2048

    f32x4 acc[2][4];
    f32x4 zero = {0.f, 0.f, 0.f, 0.f};
    #pragma unroll
    for (int i = 0; i < 2; ++i)
        #pragma unroll
        for (int j = 0; j < 4; ++j) acc[i][j] = zero;

    int aoff[2], boff[4];
    #pragma unroll
    for (int mi = 0; mi < 2; ++mi) {
        int r = w * 32 + mi * 16 + l16;
        aoff[mi] = r * 32 + (quad ^ ((r >> 1) & 3)) * 8;
    }
    #pragma unroll
    for (int ni = 0; ni < 4; ++ni) {
        int rb = ni * 16 + l16;
        boff[ni] = rb * 32 + (quad ^ ((rb >> 1) & 3)) * 8;
    }

    // stage K-step 0 (both subs) into buf 0
    #pragma unroll
    for (int sub = 0; sub < 2; ++sub) {
        #pragma unroll
        for (int i = 0; i < 2; ++i) {
            int r = sra + i * 64;
            int g = sg4 ^ ((r >> 1) & 3);
            glds16(A + (size_t)(t0 + r) * K + sub * 32 + g * 8,
                   As + sub * 4096 + adst + i * 2048);
        }
        int g = sg4 ^ ((srb >> 1) & 3);
        glds16(B + (size_t)(n0 + srb) * K + sub * 32 + g * 8,
               Bs + sub * 2048 + bdst);
    }
    __syncthreads();

    for (int kt = 0; kt < nk; ++kt) {
        if (kt + 1 < nk) {
            int k0 = (kt + 1) * 64, bi = (kt + 1) & 1;
            #pragma unroll
            for (int sub = 0; sub < 2; ++sub) {
                #pragma unroll
                for (int i = 0; i < 2; ++i) {
                    int r = sra + i * 64;
                    int g = sg4 ^ ((r >> 1) & 3);
                    glds16(A + (size_t)(t0 + r) * K + k0 + sub * 32 + g * 8,
                           As + bi * 8192 + sub * 4096 + adst + i * 2048);
                }
                int g = sg4 ^ ((srb >> 1) & 3);
                glds16(B + (size_t)(n0 + srb) * K + k0 + sub * 32 + g * 8,
                       Bs + bi * 4096 + sub * 2048 + bdst);
            }
        }
        #pragma unroll
        for (int sub = 0; sub < 2; ++sub) {
            const u16* as = As + (kt & 1) * 8192 + sub * 4096;
            const u16* bs = Bs + (kt & 1) * 4096 + sub * 2048;
            bf16x8 af[2], bfr[4];
            #pragma unroll
            for (int mi = 0; mi < 2; ++mi) af[mi]  = *(const bf16x8*)(as + aoff[mi]);
            #pragma unroll
            for (int ni = 0; ni < 4; ++ni) bfr[ni] = *(const bf16x8*)(bs + boff[ni]);
            if (!vblk) {
                #pragma unroll
                for (int mi = 0; mi < 2; ++mi)
                    #pragma unroll
                    for (int ni = 0; ni < 4; ++ni)
                        acc[mi][ni] = __builtin_amdgcn_mfma_f32_16x16x32_bf16(af[mi], bfr[ni], acc[mi][ni], 0, 0, 0);
            } else {
                #pragma unroll
                for (int mi = 0; mi < 2; ++mi)
                    #pragma unroll
                    for (int ni = 0; ni < 4; ++ni)
                        acc[mi][ni] = __builtin_amdgcn_mfma_f32_16x16x32_bf16(bfr[ni], af[mi], acc[mi][ni], 0, 0, 0);
            }
        }
        __syncthreads();
    }

    if (vblk) {
        const int kv = bx - 20;
        u16* vbase = Vt + (size_t)(b * 4 + kv) * 64 * 2048;
        const int si = (t0 + w * 32 + l16) & 2047;
        #pragma unroll
        for (int mi = 0; mi < 2; ++mi)
            #pragma unroll
            for (int ni = 0; ni < 4; ++ni) {
                int d = ni * 16 + quad * 4;
                #pragma unroll
                for (int r = 0; r < 4; ++r)
                    vbase[(size_t)(d + r) * 2048 + si + mi * 16] = f2bf(acc[mi][ni][r]);
            }
    } else {
        const bool isQ = bx < 16;
        const float sc = 0.18033688011112042f;
        const float g = isQ ? gain[bx] * sc : 1.0f;
        u16* base = isQ ? (Qb + (size_t)(b * 16 + bx) * 2048 * 64)
                        : (Kb + (size_t)(b * 4 + (bx - 16)) * 2048 * 64);
        const float eps = 1.1920929e-7f;
        const float invf0 = (float)(1.0 / pow(10000.0, (double)l16 / 32.0));
        const float invf1 = (float)(1.0 / pow(10000.0, (double)(l16 + 16) / 32.0));
        #pragma unroll
        for (int mi = 0; mi < 2; ++mi) {
            #pragma unroll
            for (int r = 0; r < 4; ++r) {
                float v0 = acc[mi][0][r], v1 = acc[mi][1][r];
                float v2 = acc[mi][2][r], v3 = acc[mi][3][r];
                float ssq = (v0 * v0 + v1 * v1) + (v2 * v2 + v3 * v3);
                #pragma unroll
                for (int m = 1; m < 16; m <<= 1) ssq += __shfl_xor(ssq, m);
                float rn = 1.0f / sqrtf(ssq * (1.0f / 64.0f) + eps);
                int si = (t0 + w * 32 + mi * 16 + quad * 4 + r) & 2047;
                float a0 = (float)si * invf0, a1 = (float)si * invf1;
                float c0 = __cosf(a0), s0 = __sinf(a0);
                float c1 = __cosf(a1), s1 = __sinf(a1);
                float x1a = v0 * rn, x2a = v2 * rn;
                float x1b = v1 * rn, x2b = v3 * rn;
                u16* row = base + (size_t)si * 64;
                row[l16]      = f2bf((x1a * c0 + x2a * s0) * g);
                row[l16 + 32] = f2bf((x2a * c0 - x1a * s0) * g);
                row[l16 + 16] = f2bf((x1b * c1 + x2b * s1) * g);
                row[l16 + 48] = f2bf((x2b * c1 - x1b * s1) * g);
            }
        }
    }
}

// ============================================================================
// 3. GEMM (proj): C[M,N] fp32 = A[M,K]bf16 @ B[N,K]^T. 128M x 64N, dbuf,
//    one barrier/iter.
// ============================================================================
__global__ __launch_bounds__(256) void gemm_bt(
    const u16* __restrict__ A, const u16* __restrict__ B,
    float* __restrict__ C, int M, int N, int K) {
    __shared__ u16 As[2][128 * 32];
    __shared__ u16 Bs[2][64 * 32];
    const int tid = threadIdx.x;
    const int lane = tid & 63, w = tid >> 6;
    const int quad = lane >> 4, l16 = lane & 15;
    const int m0 = blockIdx.y * 128, n0 = blockIdx.x * 64;
    const int wm = (w >> 1) * 64, wn = (w & 1) * 32;

    const int sra = w * 16 + (lane >> 2);
    const int srb = tid >> 2;
    const int sg4 = lane & 3;

    f32x4 acc[4][2];
    f32x4 zero = {0.f, 0.f, 0.f, 0.f};
    #pragma unroll
    for (int i = 0; i < 4; ++i) { acc[i][0] = zero; acc[i][1] = zero; }

    int aoff[4], boff[2];
    #pragma unroll
    for (int mi = 0; mi < 4; ++mi) {
        int r = wm + mi * 16 + l16;
        aoff[mi] = r * 32 + (quad ^ ((r >> 1) & 3)) * 8;
    }
    #pragma unroll
    for (int ni = 0; ni < 2; ++ni) {
        int r = wn + ni * 16 + l16;
        boff[ni] = r * 32 + (quad ^ ((r >> 1) & 3)) * 8;
    }

    const int nk = K >> 5;
    #pragma unroll
    for (int i = 0; i < 2; ++i) {
        int r = sra + i * 64;
        int g = sg4 ^ ((r >> 1) & 3);
        glds16(A + (size_t)(m0 + r) * K + g * 8, &As[0][0] + (w * 16 + i * 64) * 32 + lane * 8);
    }
    {
        int g = sg4 ^ ((srb >> 1) & 3);
        glds16(B + (size_t)(n0 + srb) * K + g * 8, &Bs[0][0] + w * 512 + lane * 8);
    }
    __syncthreads();

    for (int kt = 0; kt < nk; ++kt) {
        if (kt + 1 < nk) {
            int k0 = (kt + 1) * 32, bi = (kt + 1) & 1;
            #pragma unroll
            for (int i = 0; i < 2; ++i) {
                int r = sra + i * 64;
                int g = sg4 ^ ((r >> 1) & 3);
                glds16(A + (size_t)(m0 + r) * K + k0 + g * 8, &As[bi][0] + (w * 16 + i * 64) * 32 + lane * 8);
            }
            int g = sg4 ^ ((srb >> 1) & 3);
            glds16(B + (size_t)(n0 + srb) * K + k0 + g * 8, &Bs[bi][0] + w * 512 + lane * 8);
        }
        const u16* as = &As[kt & 1][0];
        const u16* bs = &Bs[kt & 1][0];
        bf16x8 af[4], bfr[2];
        #pragma unroll
        for (int mi = 0; mi < 4; ++mi) af[mi]  = *(const bf16x8*)(as + aoff[mi]);
        #pragma unroll
        for (int ni = 0; ni < 2; ++ni) bfr[ni] = *(const bf16x8*)(bs + boff[ni]);
        #pragma unroll
        for (int mi = 0; mi < 4; ++mi)
            #pragma unroll
            for (int ni = 0; ni < 2; ++ni)
                acc[mi][ni] = __builtin_amdgcn_mfma_f32_16x16x32_bf16(af[mi], bfr[ni], acc[mi][ni], 0, 0, 0);
        __syncthreads();
    }
    #pragma unroll
    for (int mi = 0; mi < 4; ++mi)
        #pragma unroll
        for (int ni = 0; ni < 2; ++ni) {
            int rg = m0 + wm + mi * 16 + quad * 4;
            int cg = n0 + wn + ni * 16 + l16;
            float* cp = C + (size_t)rg * N + cg;
            #pragma unroll
            for (int r = 0; r < 4; ++r) cp[(size_t)r * N] = acc[mi][ni][r];
        }
}

// ============================================================================
// 4. Flash attention (R9 structure — verified best; attn ~44us).
//    256 thr / 4 waves; each wave owns 32 Q-rows (two 16-bands), K/V LDS
//    fragments feed both bands. Q-tile 128, KV tile 64, dbuf LDS 32KB.
//    Grid 32 x 40 LPT chunks (1..8 tiles), Opart bf16, y bf16.
//    launch_bounds (256,4): kernel needs ~60 VGPR; any tighter cap (R11's
//    ",5" -> 48 VGPR) or extra live state (R8's PV pipeline) spills to
//    scratch and regresses 1.3-1.8x. Do not tighten.
// ============================================================================
__global__ __launch_bounds__(256, 4) void attn(
    const u16* __restrict__ Qb, const u16* __restrict__ Kb,
    const u16* __restrict__ Vt, const float* __restrict__ gain,
    u16* __restrict__ y, u16* __restrict__ Opart, float* __restrict__ ml) {
    __shared__ u16 Ks[2][4096];
    __shared__ u16 Vs[2][4096];
    const int hb = blockIdx.x;
    const int h = hb & 15, b = hb >> 4, kvh = h >> 2;
    const int yid = 39 - blockIdx.y;   // LPT: physical y=0 -> biggest chunk
    // chunk tables: bq (0..15), T=2bq+2 tiles, nch=ceil(T/8)
    const int nch_t[16] = {1,1,1,1,2,2,2,2,3,3,3,3,4,4,4,4};
    const int cst_t[16] = {0,1,2,3,4,6,8,10,12,15,18,21,24,28,32,36};
    int bq = 0;
    #pragma unroll
    for (int i = 1; i < 16; ++i) if (yid >= cst_t[i]) bq = i;
    const int nc = nch_t[bq], ch = yid - cst_t[bq];
    const int T = 2 * bq + 2;
    const int c0 = ch * T / nc;
    const int nj = (ch + 1) * T / nc - c0;
    const bool partial = nc > 1;
    const int q0 = bq * 128;

    const int tid = threadIdx.x, lane = tid & 63, w = tid >> 6;  // w 0..3
    const int quad = lane >> 4, l16 = lane & 15;
    const float nM = -(12.0f * fabsf(gain[h]) + 1.0f);
    const f32x4 minit = {nM, nM, nM, nM};

    const u16* Qg = Qb + ((size_t)(b * 16 + h) * 2048 + q0) * 64;
    const u16* Kg = Kb + (size_t)(b * 4 + kvh) * 2048 * 64;
    const u16* Vg = Vt + (size_t)(b * 4 + kvh) * 64 * 2048;

    // two bands per wave: q rows w*32+l16 and +16
    const int qr0 = w * 32 + l16;
    const bf16x8 qa00 = *(const bf16x8*)(Qg + (size_t)qr0 * 64 + quad * 8);
    const bf16x8 qa01 = *(const bf16x8*)(Qg + (size_t)qr0 * 64 + 32 + quad * 8);
    const bf16x8 qa10 = *(const bf16x8*)(Qg + (size_t)(qr0 + 16) * 64 + quad * 8);
    const bf16x8 qa11 = *(const bf16x8*)(Qg + (size_t)(qr0 + 16) * 64 + 32 + quad * 8);

    // staging: 256 thr x 16B x 2 passes per 8KB tile
    const int sr = tid >> 3;                 // 0..31
    const int sg = (tid & 7) ^ (sr & 7);     // XOR swizzle (same for sr+32)
    const int so = tid * 8;                  // u16 offset in LDS

    {
        int c = (c0 + nj - 1) * 64, bi = (nj - 1) & 1;
        glds16(Kg + (size_t)(c + sr) * 64 + sg * 8,        &Ks[bi][0] + so);
        glds16(Kg + (size_t)(c + sr + 32) * 64 + sg * 8,   &Ks[bi][0] + so + 2048);
        glds16(Vg + (size_t)sr * 2048 + c + sg * 8,        &Vs[bi][0] + so);
        glds16(Vg + (size_t)(sr + 32) * 2048 + c + sg * 8, &Vs[bi][0] + so + 2048);
    }
    __syncthreads();

    f32x4 o0[4], o1[4];
    f32x4 zero = {0.f, 0.f, 0.f, 0.f};
    #pragma unroll
    for (int t = 0; t < 4; ++t) { o0[t] = zero; o1[t] = zero; }
    float l0 = 0.f, l1 = 0.f;

    for (int jj = nj - 1; jj >= 0; --jj) {
        if (jj > 0) {
            int c = (c0 + jj - 1) * 64, bi = (jj - 1) & 1;
            glds16(Kg + (size_t)(c + sr) * 64 + sg * 8,        &Ks[bi][0] + so);
            glds16(Kg + (size_t)(c + sr + 32) * 64 + sg * 8,   &Ks[bi][0] + so + 2048);
            glds16(Vg + (size_t)sr * 2048 + c + sg * 8,        &Vs[bi][0] + so);
            glds16(Vg + (size_t)(sr + 32) * 2048 + c + sg * 8, &Vs[bi][0] + so + 2048);
        }
        const u16* Kt = &Ks[jj & 1][0];
        const u16* Vl = &Vs[jj & 1][0];
        const int jg = c0 + jj;
        const int d0 = 8 * bq + 2 * w - 4 * jg;   // band0 position (16-units)
        const int d1 = d0 + 1;
        if (d1 >= 0) {
            const int tm0 = d0 < 3 ? d0 : 3;       // may be -1 (band0 idle)
            const int tm1 = d1 < 3 ? d1 : 3;
            s16x4 pf0[4], pf1[4];
            float rs0 = 0.f, rs1 = 0.f;
            __builtin_amdgcn_s_setprio(1);
            #pragma unroll
            for (int t = 0; t < 4; ++t) {
                if (t <= tm1) {
                    int rk = t * 16 + l16;
                    bf16x8 kb0 = *(const bf16x8*)(Kt + rk * 64 + ((quad ^ (rk & 7)) * 8));
                    bf16x8 kb1 = *(const bf16x8*)(Kt + rk * 64 + (((quad + 4) ^ (rk & 7)) * 8));
                    if (t <= tm0) {
                        f32x4 s = __builtin_amdgcn_mfma_f32_16x16x32_bf16(kb0, qa00, minit, 0, 0, 0);
                        s = __builtin_amdgcn_mfma_f32_16x16x32_bf16(kb1, qa01, s, 0, 0, 0);
                        if (t == d0) {
                            #pragma unroll
                            for (int r = 0; r < 4; ++r)
                                if (quad * 4 + r > l16) s[r] = -1e30f;
                        }
                        float p0 = __builtin_amdgcn_exp2f(s[0]);
                        float p1 = __builtin_amdgcn_exp2f(s[1]);
                        float p2 = __builtin_amdgcn_exp2f(s[2]);
                        float p3 = __builtin_amdgcn_exp2f(s[3]);
                        rs0 += (p0 + p1) + (p2 + p3);
                        pf0[t] = pack_bf4(p0, p1, p2, p3);
                    }
                    {
                        f32x4 s = __builtin_amdgcn_mfma_f32_16x16x32_bf16(kb0, qa10, minit, 0, 0, 0);
                        s = __builtin_amdgcn_mfma_f32_16x16x32_bf16(kb1, qa11, s, 0, 0, 0);
                        if (t == d1) {
                            #pragma unroll
                            for (int r = 0; r < 4; ++r)
                                if (quad * 4 + r > l16) s[r] = -1e30f;
                        }
                        float p0 = __builtin_amdgcn_exp2f(s[0]);
                        float p1 = __builtin_amdgcn_exp2f(s[1]);
                        float p2 = __builtin_amdgcn_exp2f(s[2]);
                        float p3 = __builtin_amdgcn_exp2f(s[3]);
                        rs1 += (p0 + p1) + (p2 + p3);
                        pf1[t] = pack_bf4(p0, p1, p2, p3);
                    }
                }
            }
            l0 += rs0; l1 += rs1;
            #pragma unroll
            for (int dt = 0; dt < 4; ++dt) {
                int rv = dt * 16 + l16;
                #pragma unroll
                for (int kt = 0; kt < 4; ++kt) {
                    if (kt <= tm1) {
                        int gv = 2 * kt + (quad >> 1);
                        s16x4 va = *(const s16x4*)(Vl + rv * 64 + ((gv ^ (rv & 7)) * 8) + (quad & 1) * 4);
                        if (kt <= tm0) o0[dt] = MFMA16(va, pf0[kt], o0[dt]);
                        o1[dt] = MFMA16(va, pf1[kt], o1[dt]);
                    }
                }
            }
            __builtin_amdgcn_s_setprio(0);
        }
        __syncthreads();
    }

    // finish row-sums: quads hold disjoint k-slices
    l0 += __shfl_xor(l0, 16);
    l0 += __shfl_xor(l0, 32);
    l1 += __shfl_xor(l1, 16);
    l1 += __shfl_xor(l1, 32);

    const int q = w * 32 + l16;
    if (!partial) {
        const float inv0 = 1.0f / l0, inv1 = 1.0f / l1;
        const size_t row0 = (size_t)b * 2048 + q0 + q;
        u16* yp0 = y + row0 * 1024 + h * 64 + quad * 4;
        u16* yp1 = y + (row0 + 16) * 1024 + h * 64 + quad * 4;
        #pragma unroll
        for (int dt = 0; dt < 4; ++dt) {
            f32x4 a = o0[dt] * inv0;
            *(s16x4*)(yp0 + dt * 16) = pack_bf4(a[0], a[1], a[2], a[3]);
            f32x4 c = o1[dt] * inv1;
            *(s16x4*)(yp1 + dt * 16) = pack_bf4(c[0], c[1], c[2], c[3]);
        }
    } else {
        const int slot = hb * 36 + (yid - 4);
        u16* Op = Opart + (size_t)slot * 8192;
        #pragma unroll
        for (int dt = 0; dt < 4; ++dt) {
            *(s16x4*)(Op + q * 64 + dt * 16 + quad * 4) =
                pack_bf4(o0[dt][0], o0[dt][1], o0[dt][2], o0[dt][3]);
            *(s16x4*)(Op + (q + 16) * 64 + dt * 16 + quad * 4) =
                pack_bf4(o1[dt][0], o1[dt][1], o1[dt][2], o1[dt][3]);
        }
        if (quad == 0) {
            ml[slot * 128 + q] = l0;
            ml[slot * 128 + q + 16] = l1;
        }
    }
}

// ============================================================================
// 5. rmsnorm_merge: rows s<512 read y (BF16); rows s>=512 combine split-K
//    partials (nch[bq] chunks, 2..4; Opart BF16, l fp32, accumulate fp32).
// ============================================================================
__global__ __launch_bounds__(256) void rmsnorm_merge(
    const u16* __restrict__ y, const u16* __restrict__ Opart,
    const float* __restrict__ ml, u16* __restrict__ yb) {
    __shared__ float red[4];
    const int row = blockIdx.x, tid = threadIdx.x;
    const int b = row >> 11, s = row & 2047;
    float4 v;
    if (s < 512) {
        s16x4 pv = *(const s16x4*)(y + (size_t)row * 1024 + tid * 4);
        v.x = bf2f((u16)pv[0]); v.y = bf2f((u16)pv[1]);
        v.z = bf2f((u16)pv[2]); v.w = bf2f((u16)pv[3]);
    } else {
        const int nch_t[16] = {1,1,1,1,2,2,2,2,3,3,3,3,4,4,4,4};
        const int cst_t[16] = {0,1,2,3,4,6,8,10,12,15,18,21,24,28,32,36};
        const int bq = s >> 7, q = s & 127;
        const int e = tid * 4, h = e >> 6, dh = e & 63;
        const int n = nch_t[bq];
        const int slot0 = (b * 16 + h) * 36 + (cst_t[bq] - 4);
        float l = 0.f;
        f32x4 xa = {0.f, 0.f, 0.f, 0.f};
        const u16* P = Opart + (size_t)slot0 * 8192 + q * 64 + dh;
        for (int c = 0; c < n; ++c) {
            l += ml[(size_t)(slot0 + c) * 128 + q];
            s16x4 pv = *(const s16x4*)(P + (size_t)c * 8192);
            f32x4 pf = {bf2f((u16)pv[0]), bf2f((u16)pv[1]),
                        bf2f((u16)pv[2]), bf2f((u16)pv[3])};
            xa += pf;
        }
        float inv = 1.0f / l;
        v.x = xa[0] * inv; v.y = xa[1] * inv; v.z = xa[2] * inv; v.w = xa[3] * inv;
    }
    float ss = v.x * v.x + v.y * v.y + v.z * v.z + v.w * v.w;
    #pragma unroll
    for (int m = 1; m < 64; m <<= 1) ss += __shfl_xor(ss, m);
    if ((tid & 63) == 0) red[tid >> 6] = ss;
    __syncthreads();
    float tot = red[0] + red[1] + red[2] + red[3];
    float rn = 1.0f / sqrtf(tot * (1.0f / 1024.0f) + 1.1920929e-7f);
    u16 o[4] = {f2bf(v.x * rn), f2bf(v.y * rn), f2bf(v.z * rn), f2bf(v.w * rn)};
    *(uint2*)(yb + (size_t)row * 1024 + tid * 4) = *(const uint2*)o;
}

// ============================================================================
// launch — workspace (peak ~51 MB; ws is 256 MiB per harness poison-fill):
//   [0,      2.10M)  wproj_b  (prep -> gemm2)
//   [2.10M, 10.49M)  xb (prep -> gemm_qkv); then y BF16 @2.10M..10.49M
//                    (attn -> rms; xb dead by attn time)
//   [10.49M,13.63M)  wqkv_b (prep -> gemm_qkv)
//   [18.87M,27.26M)  Qb (gemm_qkv -> attn); then yb (rms -> gemm2)
//   [27.26M,29.36M)  Kb   [29.36M,31.46M) Vt
//   [31.46M,50.33M)  Opart (attn -> rms; 32 hb x 36 slots x 8192 BF16)
//   [50.33M,50.92M)  ml (1152 slots x 128 f32)
// ============================================================================
extern "C" void kernel_launch(void* const* d_in, const int* in_sizes, int n_in,
                              void* d_out, int out_size, void* d_ws, size_t ws_size,
                              hipStream_t stream) {
    const float* x      = (const float*)d_in[0];
    const float* w_qkv  = (const float*)d_in[1];
    const float* w_proj = (const float*)d_in[2];
    const float* q_gain = (const float*)d_in[3];
    float* out = (float*)d_out;
    char* ws = (char*)d_ws;

    u16*   wproj_b = (u16*)(ws);
    u16*   xb      = (u16*)(ws + 2097152);
    u16*   y       = (u16*)(ws + 2097152);
    u16*   wqkv_b  = (u16*)(ws + 10485760);
    u16*   Qb      = (u16*)(ws + 18874368);
    u16*   yb      = (u16*)(ws + 18874368);
    u16*   Kb      = (u16*)(ws + 27262976);
    u16*   Vt      = (u16*)(ws + 29360128);
    u16*   Opart   = (u16*)(ws + 31457280);
    float* mlb     = (float*)(ws + 50331648);

    prep<<<3328, 256, 0, stream>>>(w_qkv, w_proj, x, wqkv_b, wproj_b, xb);
    gemm_qkv<<<dim3(24, 32), 256, 0, stream>>>(xb, wqkv_b, q_gain, Qb, Kb, Vt);
    attn<<<dim3(32, 40), 256, 0, stream>>>(Qb, Kb, Vt, q_gain, y, Opart, mlb);
    rmsnorm_merge<<<4096, 256, 0, stream>>>(y, Opart, mlb, yb);
    gemm_bt<<<dim3(16, 32), 256, 0, stream>>>(yb, wproj_b, out, 4096, 1024, 1024);
}

// Round 15
// 167.738 us; speedup vs baseline: 1.0373x; 1.0107x over previous
//
#include <hip/hip_runtime.h>
#include <cstdint>

typedef unsigned short u16;
typedef __bf16 bf16x8 __attribute__((ext_vector_type(8)));
typedef __bf16 bf16x2 __attribute__((ext_vector_type(2)));
typedef short s16x4 __attribute__((ext_vector_type(4)));
typedef int s32x2 __attribute__((ext_vector_type(2)));
typedef float f32x4 __attribute__((ext_vector_type(4)));

// ---- bf16 helpers (RTNE, matching XLA/ml_dtypes) ----
__device__ __forceinline__ u16 f2bf(float f) {
    unsigned u = __float_as_uint(f);
    u = (u + 0x7fffu + ((u >> 16) & 1u)) >> 16;
    return (u16)u;
}
__device__ __forceinline__ float bf2f(u16 h) {
    return __uint_as_float(((unsigned)h) << 16);
}

// async global->LDS, 16B per lane; LDS dest = wave-uniform base + lane*16
__device__ __forceinline__ void glds16(const u16* g, u16* l) {
    __builtin_amdgcn_global_load_lds(
        (const __attribute__((address_space(1))) void*)g,
        (__attribute__((address_space(3))) void*)l, 16, 0, 0);
}

// pack 4 floats -> 4 bf16 via native casts (gfx950: v_cvt_pk_bf16_f32, RTNE)
__device__ __forceinline__ s16x4 pack_bf4(float p0, float p1, float p2, float p3) {
    bf16x2 lo = {(__bf16)p0, (__bf16)p1};
    bf16x2 hi = {(__bf16)p2, (__bf16)p3};
    s32x2 pk = {__builtin_bit_cast(int, lo), __builtin_bit_cast(int, hi)};
    return __builtin_bit_cast(s16x4, pk);
}

#if __has_builtin(__builtin_amdgcn_mfma_f32_16x16x16bf16_1k)
#define MFMA16(a, b, c) __builtin_amdgcn_mfma_f32_16x16x16bf16_1k(a, b, c, 0, 0, 0)
#else
static __device__ __forceinline__ f32x4 mfma16_asm(s16x4 a, s16x4 b, f32x4 c) {
    asm("v_mfma_f32_16x16x16_bf16 %0, %1, %2, %0" : "+v"(c) : "v"(a), "v"(b));
    return c;
}
#define MFMA16(a, b, c) mfma16_asm(a, b, c)
#endif

// ============================================================================
// 1. prep: ternary-quantize both weights (8 elems/lane) + cast x to bf16.
//    GRID = 1280 quant + 2048 cast = 3328.
// ============================================================================
__global__ __launch_bounds__(256) void prep(
    const float* __restrict__ w_qkv, const float* __restrict__ w_proj,
    const float* __restrict__ x,
    u16* __restrict__ wqkv_b, u16* __restrict__ wproj_b, u16* __restrict__ xb) {
    int bid = blockIdx.x;
    if (bid < 1280) {
        const float* w; u16* o; size_t base;
        if (bid < 768) { w = w_qkv; o = wqkv_b; base = (size_t)bid * 2048; }
        else { w = w_proj; o = wproj_b; base = (size_t)(bid - 768) * 2048; }
        size_t i = base + (size_t)threadIdx.x * 8;
        float4 A = *(const float4*)(w + i);
        float4 B = *(const float4*)(w + i + 4);
        float wf[8] = {A.x, A.y, A.z, A.w, B.x, B.y, B.z, B.w};
        float wbf[8], ab[8];
        #pragma unroll
        for (int e = 0; e < 8; ++e) { wbf[e] = bf2f(f2bf(wf[e])); ab[e] = fabsf(wbf[e]); }
        float s = ((ab[0] + ab[1]) + (ab[2] + ab[3])) + ((ab[4] + ab[5]) + (ab[6] + ab[7]));
        s += __shfl_xor(s, 1);
        s += __shfl_xor(s, 2);
        s += __shfl_xor(s, 4);   // 8-lane cluster = one 64-elem group
        float scale = bf2f(f2bf(s * (1.0f / 64.0f)));
        if (scale < 1e-8f) scale = 1e-8f;
        u16 ov[8];
        #pragma unroll
        for (int e = 0; e < 8; ++e) {
            float t = bf2f(f2bf(wbf[e] / scale));
            float q = rintf(t);
            q = fminf(1.0f, fmaxf(-1.0f, q));
            float d = bf2f(f2bf(q * scale - wbf[e]));
            ov[e] = f2bf(wbf[e] + d);
        }
        *(int4*)(o + i) = *(const int4*)ov;
    } else {
        size_t i = ((size_t)(bid - 1280) * 256 + threadIdx.x) * 8;
        float4 a = *(const float4*)(x + i);
        float4 b = *(const float4*)(x + i + 4);
        u16 o[8] = {f2bf(a.x), f2bf(a.y), f2bf(a.z), f2bf(a.w),
                    f2bf(b.x), f2bf(b.y), f2bf(b.z), f2bf(b.w)};
        *(int4*)(xb + i) = *(const int4*)o;
    }
}

// ============================================================================
// 2. gemm_qkv: xb[4096x1024] @ wqkv^T with FUSED RMSNorm+RoPE+gain epilogue.
//    Tile 128M x 64N, grid 24x32 = 768 blocks = 3/CU. BK=64 (R14 win:
//    barriers/block 32->16, vmcnt-drain amortized 2x; 174->169.5us).
//    LDS 48KB.
// ============================================================================
__global__ __launch_bounds__(256) void gemm_qkv(
    const u16* __restrict__ A, const u16* __restrict__ B,
    const float* __restrict__ gain,
    u16* __restrict__ Qb, u16* __restrict__ Kb, u16* __restrict__ Vt) {
    __shared__ u16 As[2 * 8192];   // 2 bufs x (2 sub x 128x32)
    __shared__ u16 Bs[2 * 4096];   // 2 bufs x (2 sub x 64x32)
    const int tid = threadIdx.x;
    const int lane = tid & 63, w = tid >> 6;
    const int quad = lane >> 4, l16 = lane & 15;
    const int bx = blockIdx.x, by = blockIdx.y;
    const int n0 = bx * 64, t0 = by * 128;
    const bool vblk = bx >= 20;
    const int K = 1024, nk = 16;   // 16 K-steps of 64
    const int b = by >> 4;           // batch (128-row tiles; 16 per batch)

    const int sra = w * 16 + (lane >> 2);   // A local row, +i*64
    const int srb = tid >> 2;               // B local row (0..63)
    const int sg4 = lane & 3;
    const int adst = (w * 16) * 32 + lane * 8;   // + i*64*32, + sub*4096
    const int bdst = w * 512 + lane * 8;         // + sub*2048

    f32x4 acc[2][4];
    f32x4 zero = {0.f, 0.f, 0.f, 0.f};
    #pragma unroll
    for (int i = 0; i < 2; ++i)
        #pragma unroll
        for (int j = 0; j < 4; ++j) acc[i][j] = zero;

    int aoff[2], boff[4];
    #pragma unroll
    for (int mi = 0; mi < 2; ++mi) {
        int r = w * 32 + mi * 16 + l16;
        aoff[mi] = r * 32 + (quad ^ ((r >> 1) & 3)) * 8;
    }
    #pragma unroll
    for (int ni = 0; ni < 4; ++ni) {
        int rb = ni * 16 + l16;
        boff[ni] = rb * 32 + (quad ^ ((rb >> 1) & 3)) * 8;
    }

    // stage K-step 0 (both subs) into buf 0
    #pragma unroll
    for (int sub = 0; sub < 2; ++sub) {
        #pragma unroll
        for (int i = 0; i < 2; ++i) {
            int r = sra + i * 64;
            int g = sg4 ^ ((r >> 1) & 3);
            glds16(A + (size_t)(t0 + r) * K + sub * 32 + g * 8,
                   As + sub * 4096 + adst + i * 2048);
        }
        int g = sg4 ^ ((srb >> 1) & 3);
        glds16(B + (size_t)(n0 + srb) * K + sub * 32 + g * 8,
               Bs + sub * 2048 + bdst);
    }
    __syncthreads();

    for (int kt = 0; kt < nk; ++kt) {
        if (kt + 1 < nk) {
            int k0 = (kt + 1) * 64, bi = (kt + 1) & 1;
            #pragma unroll
            for (int sub = 0; sub < 2; ++sub) {
                #pragma unroll
                for (int i = 0; i < 2; ++i) {
                    int r = sra + i * 64;
                    int g = sg4 ^ ((r >> 1) & 3);
                    glds16(A + (size_t)(t0 + r) * K + k0 + sub * 32 + g * 8,
                           As + bi * 8192 + sub * 4096 + adst + i * 2048);
                }
                int g = sg4 ^ ((srb >> 1) & 3);
                glds16(B + (size_t)(n0 + srb) * K + k0 + sub * 32 + g * 8,
                       Bs + bi * 4096 + sub * 2048 + bdst);
            }
        }
        #pragma unroll
        for (int sub = 0; sub < 2; ++sub) {
            const u16* as = As + (kt & 1) * 8192 + sub * 4096;
            const u16* bs = Bs + (kt & 1) * 4096 + sub * 2048;
            bf16x8 af[2], bfr[4];
            #pragma unroll
            for (int mi = 0; mi < 2; ++mi) af[mi]  = *(const bf16x8*)(as + aoff[mi]);
            #pragma unroll
            for (int ni = 0; ni < 4; ++ni) bfr[ni] = *(const bf16x8*)(bs + boff[ni]);
            if (!vblk) {
                #pragma unroll
                for (int mi = 0; mi < 2; ++mi)
                    #pragma unroll
                    for (int ni = 0; ni < 4; ++ni)
                        acc[mi][ni] = __builtin_amdgcn_mfma_f32_16x16x32_bf16(af[mi], bfr[ni], acc[mi][ni], 0, 0, 0);
            } else {
                #pragma unroll
                for (int mi = 0; mi < 2; ++mi)
                    #pragma unroll
                    for (int ni = 0; ni < 4; ++ni)
                        acc[mi][ni] = __builtin_amdgcn_mfma_f32_16x16x32_bf16(bfr[ni], af[mi], acc[mi][ni], 0, 0, 0);
            }
        }
        __syncthreads();
    }

    if (vblk) {
        const int kv = bx - 20;
        u16* vbase = Vt + (size_t)(b * 4 + kv) * 64 * 2048;
        const int si = (t0 + w * 32 + l16) & 2047;
        #pragma unroll
        for (int mi = 0; mi < 2; ++mi)
            #pragma unroll
            for (int ni = 0; ni < 4; ++ni) {
                int d = ni * 16 + quad * 4;
                #pragma unroll
                for (int r = 0; r < 4; ++r)
                    vbase[(size_t)(d + r) * 2048 + si + mi * 16] = f2bf(acc[mi][ni][r]);
            }
    } else {
        const bool isQ = bx < 16;
        const float sc = 0.18033688011112042f;
        const float g = isQ ? gain[bx] * sc : 1.0f;
        u16* base = isQ ? (Qb + (size_t)(b * 16 + bx) * 2048 * 64)
                        : (Kb + (size_t)(b * 4 + (bx - 16)) * 2048 * 64);
        const float eps = 1.1920929e-7f;
        const float invf0 = (float)(1.0 / pow(10000.0, (double)l16 / 32.0));
        const float invf1 = (float)(1.0 / pow(10000.0, (double)(l16 + 16) / 32.0));
        #pragma unroll
        for (int mi = 0; mi < 2; ++mi) {
            #pragma unroll
            for (int r = 0; r < 4; ++r) {
                float v0 = acc[mi][0][r], v1 = acc[mi][1][r];
                float v2 = acc[mi][2][r], v3 = acc[mi][3][r];
                float ssq = (v0 * v0 + v1 * v1) + (v2 * v2 + v3 * v3);
                #pragma unroll
                for (int m = 1; m < 16; m <<= 1) ssq += __shfl_xor(ssq, m);
                float rn = 1.0f / sqrtf(ssq * (1.0f / 64.0f) + eps);
                int si = (t0 + w * 32 + mi * 16 + quad * 4 + r) & 2047;
                float a0 = (float)si * invf0, a1 = (float)si * invf1;
                float c0 = __cosf(a0), s0 = __sinf(a0);
                float c1 = __cosf(a1), s1 = __sinf(a1);
                float x1a = v0 * rn, x2a = v2 * rn;
                float x1b = v1 * rn, x2b = v3 * rn;
                u16* row = base + (size_t)si * 64;
                row[l16]      = f2bf((x1a * c0 + x2a * s0) * g);
                row[l16 + 32] = f2bf((x2a * c0 - x1a * s0) * g);
                row[l16 + 16] = f2bf((x1b * c1 + x2b * s1) * g);
                row[l16 + 48] = f2bf((x2b * c1 - x1b * s1) * g);
            }
        }
    }
}

// ============================================================================
// 3. GEMM (proj): C[M,N] fp32 = A[M,K]bf16 @ B[N,K]^T. 128M x 64N.
//    NEW (R15): BK=64, same transformation as gemm_qkv's R14 win —
//    2 sub-tiles per buffer, 2 MFMA sub-steps per barrier, barriers 32->16.
//    gemm_bt runs at only 2 blocks/CU so the drain amortization matters
//    even more. LDS 48KB.
// ============================================================================
__global__ __launch_bounds__(256) void gemm_bt(
    const u16* __restrict__ A, const u16* __restrict__ B,
    float* __restrict__ C, int M, int N, int K) {
    __shared__ u16 As[2 * 8192];
    __shared__ u16 Bs[2 * 4096];
    const int tid = threadIdx.x;
    const int lane = tid & 63, w = tid >> 6;
    const int quad = lane >> 4, l16 = lane & 15;
    const int m0 = blockIdx.y * 128, n0 = blockIdx.x * 64;
    const int wm = (w >> 1) * 64, wn = (w & 1) * 32;

    const int sra = w * 16 + (lane >> 2);
    const int srb = tid >> 2;
    const int sg4 = lane & 3;
    const int adst = (w * 16) * 32 + lane * 8;
    const int bdst = w * 512 + lane * 8;

    f32x4 acc[4][2];
    f32x4 zero = {0.f, 0.f, 0.f, 0.f};
    #pragma unroll
    for (int i = 0; i < 4; ++i) { acc[i][0] = zero; acc[i][1] = zero; }

    int aoff[4], boff[2];
    #pragma unroll
    for (int mi = 0; mi < 4; ++mi) {
        int r = wm + mi * 16 + l16;
        aoff[mi] = r * 32 + (quad ^ ((r >> 1) & 3)) * 8;
    }
    #pragma unroll
    for (int ni = 0; ni < 2; ++ni) {
        int r = wn + ni * 16 + l16;
        boff[ni] = r * 32 + (quad ^ ((r >> 1) & 3)) * 8;
    }

    const int nk = K >> 6;   // 64-col K-steps
    #pragma unroll
    for (int sub = 0; sub < 2; ++sub) {
        #pragma unroll
        for (int i = 0; i < 2; ++i) {
            int r = sra + i * 64;
            int g = sg4 ^ ((r >> 1) & 3);
            glds16(A + (size_t)(m0 + r) * K + sub * 32 + g * 8,
                   As + sub * 4096 + adst + i * 2048);
        }
        int g = sg4 ^ ((srb >> 1) & 3);
        glds16(B + (size_t)(n0 + srb) * K + sub * 32 + g * 8,
               Bs + sub * 2048 + bdst);
    }
    __syncthreads();

    for (int kt = 0; kt < nk; ++kt) {
        if (kt + 1 < nk) {
            int k0 = (kt + 1) * 64, bi = (kt + 1) & 1;
            #pragma unroll
            for (int sub = 0; sub < 2; ++sub) {
                #pragma unroll
                for (int i = 0; i < 2; ++i) {
                    int r = sra + i * 64;
                    int g = sg4 ^ ((r >> 1) & 3);
                    glds16(A + (size_t)(m0 + r) * K + k0 + sub * 32 + g * 8,
                           As + bi * 8192 + sub * 4096 + adst + i * 2048);
                }
                int g = sg4 ^ ((srb >> 1) & 3);
                glds16(B + (size_t)(n0 + srb) * K + k0 + sub * 32 + g * 8,
                       Bs + bi * 4096 + sub * 2048 + bdst);
            }
        }
        #pragma unroll
        for (int sub = 0; sub < 2; ++sub) {
            const u16* as = As + (kt & 1) * 8192 + sub * 4096;
            const u16* bs = Bs + (kt & 1) * 4096 + sub * 2048;
            bf16x8 af[4], bfr[2];
            #pragma unroll
            for (int mi = 0; mi < 4; ++mi) af[mi]  = *(const bf16x8*)(as + aoff[mi]);
            #pragma unroll
            for (int ni = 0; ni < 2; ++ni) bfr[ni] = *(const bf16x8*)(bs + boff[ni]);
            #pragma unroll
            for (int mi = 0; mi < 4; ++mi)
                #pragma unroll
                for (int ni = 0; ni < 2; ++ni)
                    acc[mi][ni] = __builtin_amdgcn_mfma_f32_16x16x32_bf16(af[mi], bfr[ni], acc[mi][ni], 0, 0, 0);
        }
        __syncthreads();
    }
    #pragma unroll
    for (int mi = 0; mi < 4; ++mi)
        #pragma unroll
        for (int ni = 0; ni < 2; ++ni) {
            int rg = m0 + wm + mi * 16 + quad * 4;
            int cg = n0 + wn + ni * 16 + l16;
            float* cp = C + (size_t)rg * N + cg;
            #pragma unroll
            for (int r = 0; r < 4; ++r) cp[(size_t)r * N] = acc[mi][ni][r];
        }
}

// ============================================================================
// 4. Flash attention (R9 structure — verified best; attn ~44us).
//    256 thr / 4 waves; each wave owns 32 Q-rows (two 16-bands), K/V LDS
//    fragments feed both bands. Q-tile 128, KV tile 64, dbuf LDS 32KB.
//    Grid 32 x 40 LPT chunks (1..8 tiles), Opart bf16, y bf16.
//    launch_bounds (256,4): kernel needs ~60 VGPR; any tighter cap (R11's
//    ",5" -> 48 VGPR) or extra live state (R8's PV pipeline) spills to
//    scratch and regresses 1.3-1.8x. Do not tighten.
// ============================================================================
__global__ __launch_bounds__(256, 4) void attn(
    const u16* __restrict__ Qb, const u16* __restrict__ Kb,
    const u16* __restrict__ Vt, const float* __restrict__ gain,
    u16* __restrict__ y, u16* __restrict__ Opart, float* __restrict__ ml) {
    __shared__ u16 Ks[2][4096];
    __shared__ u16 Vs[2][4096];
    const int hb = blockIdx.x;
    const int h = hb & 15, b = hb >> 4, kvh = h >> 2;
    const int yid = 39 - blockIdx.y;   // LPT: physical y=0 -> biggest chunk
    // chunk tables: bq (0..15), T=2bq+2 tiles, nch=ceil(T/8)
    const int nch_t[16] = {1,1,1,1,2,2,2,2,3,3,3,3,4,4,4,4};
    const int cst_t[16] = {0,1,2,3,4,6,8,10,12,15,18,21,24,28,32,36};
    int bq = 0;
    #pragma unroll
    for (int i = 1; i < 16; ++i) if (yid >= cst_t[i]) bq = i;
    const int nc = nch_t[bq], ch = yid - cst_t[bq];
    const int T = 2 * bq + 2;
    const int c0 = ch * T / nc;
    const int nj = (ch + 1) * T / nc - c0;
    const bool partial = nc > 1;
    const int q0 = bq * 128;

    const int tid = threadIdx.x, lane = tid & 63, w = tid >> 6;  // w 0..3
    const int quad = lane >> 4, l16 = lane & 15;
    const float nM = -(12.0f * fabsf(gain[h]) + 1.0f);
    const f32x4 minit = {nM, nM, nM, nM};

    const u16* Qg = Qb + ((size_t)(b * 16 + h) * 2048 + q0) * 64;
    const u16* Kg = Kb + (size_t)(b * 4 + kvh) * 2048 * 64;
    const u16* Vg = Vt + (size_t)(b * 4 + kvh) * 64 * 2048;

    // two bands per wave: q rows w*32+l16 and +16
    const int qr0 = w * 32 + l16;
    const bf16x8 qa00 = *(const bf16x8*)(Qg + (size_t)qr0 * 64 + quad * 8);
    const bf16x8 qa01 = *(const bf16x8*)(Qg + (size_t)qr0 * 64 + 32 + quad * 8);
    const bf16x8 qa10 = *(const bf16x8*)(Qg + (size_t)(qr0 + 16) * 64 + quad * 8);
    const bf16x8 qa11 = *(const bf16x8*)(Qg + (size_t)(qr0 + 16) * 64 + 32 + quad * 8);

    // staging: 256 thr x 16B x 2 passes per 8KB tile
    const int sr = tid >> 3;                 // 0..31
    const int sg = (tid & 7) ^ (sr & 7);     // XOR swizzle (same for sr+32)
    const int so = tid * 8;                  // u16 offset in LDS

    {
        int c = (c0 + nj - 1) * 64, bi = (nj - 1) & 1;
        glds16(Kg + (size_t)(c + sr) * 64 + sg * 8,        &Ks[bi][0] + so);
        glds16(Kg + (size_t)(c + sr + 32) * 64 + sg * 8,   &Ks[bi][0] + so + 2048);
        glds16(Vg + (size_t)sr * 2048 + c + sg * 8,        &Vs[bi][0] + so);
        glds16(Vg + (size_t)(sr + 32) * 2048 + c + sg * 8, &Vs[bi][0] + so + 2048);
    }
    __syncthreads();

    f32x4 o0[4], o1[4];
    f32x4 zero = {0.f, 0.f, 0.f, 0.f};
    #pragma unroll
    for (int t = 0; t < 4; ++t) { o0[t] = zero; o1[t] = zero; }
    float l0 = 0.f, l1 = 0.f;

    for (int jj = nj - 1; jj >= 0; --jj) {
        if (jj > 0) {
            int c = (c0 + jj - 1) * 64, bi = (jj - 1) & 1;
            glds16(Kg + (size_t)(c + sr) * 64 + sg * 8,        &Ks[bi][0] + so);
            glds16(Kg + (size_t)(c + sr + 32) * 64 + sg * 8,   &Ks[bi][0] + so + 2048);
            glds16(Vg + (size_t)sr * 2048 + c + sg * 8,        &Vs[bi][0] + so);
            glds16(Vg + (size_t)(sr + 32) * 2048 + c + sg * 8, &Vs[bi][0] + so + 2048);
        }
        const u16* Kt = &Ks[jj & 1][0];
        const u16* Vl = &Vs[jj & 1][0];
        const int jg = c0 + jj;
        const int d0 = 8 * bq + 2 * w - 4 * jg;   // band0 position (16-units)
        const int d1 = d0 + 1;
        if (d1 >= 0) {
            const int tm0 = d0 < 3 ? d0 : 3;       // may be -1 (band0 idle)
            const int tm1 = d1 < 3 ? d1 : 3;
            s16x4 pf0[4], pf1[4];
            float rs0 = 0.f, rs1 = 0.f;
            __builtin_amdgcn_s_setprio(1);
            #pragma unroll
            for (int t = 0; t < 4; ++t) {
                if (t <= tm1) {
                    int rk = t * 16 + l16;
                    bf16x8 kb0 = *(const bf16x8*)(Kt + rk * 64 + ((quad ^ (rk & 7)) * 8));
                    bf16x8 kb1 = *(const bf16x8*)(Kt + rk * 64 + (((quad + 4) ^ (rk & 7)) * 8));
                    if (t <= tm0) {
                        f32x4 s = __builtin_amdgcn_mfma_f32_16x16x32_bf16(kb0, qa00, minit, 0, 0, 0);
                        s = __builtin_amdgcn_mfma_f32_16x16x32_bf16(kb1, qa01, s, 0, 0, 0);
                        if (t == d0) {
                            #pragma unroll
                            for (int r = 0; r < 4; ++r)
                                if (quad * 4 + r > l16) s[r] = -1e30f;
                        }
                        float p0 = __builtin_amdgcn_exp2f(s[0]);
                        float p1 = __builtin_amdgcn_exp2f(s[1]);
                        float p2 = __builtin_amdgcn_exp2f(s[2]);
                        float p3 = __builtin_amdgcn_exp2f(s[3]);
                        rs0 += (p0 + p1) + (p2 + p3);
                        pf0[t] = pack_bf4(p0, p1, p2, p3);
                    }
                    {
                        f32x4 s = __builtin_amdgcn_mfma_f32_16x16x32_bf16(kb0, qa10, minit, 0, 0, 0);
                        s = __builtin_amdgcn_mfma_f32_16x16x32_bf16(kb1, qa11, s, 0, 0, 0);
                        if (t == d1) {
                            #pragma unroll
                            for (int r = 0; r < 4; ++r)
                                if (quad * 4 + r > l16) s[r] = -1e30f;
                        }
                        float p0 = __builtin_amdgcn_exp2f(s[0]);
                        float p1 = __builtin_amdgcn_exp2f(s[1]);
                        float p2 = __builtin_amdgcn_exp2f(s[2]);
                        float p3 = __builtin_amdgcn_exp2f(s[3]);
                        rs1 += (p0 + p1) + (p2 + p3);
                        pf1[t] = pack_bf4(p0, p1, p2, p3);
                    }
                }
            }
            l0 += rs0; l1 += rs1;
            #pragma unroll
            for (int dt = 0; dt < 4; ++dt) {
                int rv = dt * 16 + l16;
                #pragma unroll
                for (int kt = 0; kt < 4; ++kt) {
                    if (kt <= tm1) {
                        int gv = 2 * kt + (quad >> 1);
                        s16x4 va = *(const s16x4*)(Vl + rv * 64 + ((gv ^ (rv & 7)) * 8) + (quad & 1) * 4);
                        if (kt <= tm0) o0[dt] = MFMA16(va, pf0[kt], o0[dt]);
                        o1[dt] = MFMA16(va, pf1[kt], o1[dt]);
                    }
                }
            }
            __builtin_amdgcn_s_setprio(0);
        }
        __syncthreads();
    }

    // finish row-sums: quads hold disjoint k-slices
    l0 += __shfl_xor(l0, 16);
    l0 += __shfl_xor(l0, 32);
    l1 += __shfl_xor(l1, 16);
    l1 += __shfl_xor(l1, 32);

    const int q = w * 32 + l16;
    if (!partial) {
        const float inv0 = 1.0f / l0, inv1 = 1.0f / l1;
        const size_t row0 = (size_t)b * 2048 + q0 + q;
        u16* yp0 = y + row0 * 1024 + h * 64 + quad * 4;
        u16* yp1 = y + (row0 + 16) * 1024 + h * 64 + quad * 4;
        #pragma unroll
        for (int dt = 0; dt < 4; ++dt) {
            f32x4 a = o0[dt] * inv0;
            *(s16x4*)(yp0 + dt * 16) = pack_bf4(a[0], a[1], a[2], a[3]);
            f32x4 c = o1[dt] * inv1;
            *(s16x4*)(yp1 + dt * 16) = pack_bf4(c[0], c[1], c[2], c[3]);
        }
    } else {
        const int slot = hb * 36 + (yid - 4);
        u16* Op = Opart + (size_t)slot * 8192;
        #pragma unroll
        for (int dt = 0; dt < 4; ++dt) {
            *(s16x4*)(Op + q * 64 + dt * 16 + quad * 4) =
                pack_bf4(o0[dt][0], o0[dt][1], o0[dt][2], o0[dt][3]);
            *(s16x4*)(Op + (q + 16) * 64 + dt * 16 + quad * 4) =
                pack_bf4(o1[dt][0], o1[dt][1], o1[dt][2], o1[dt][3]);
        }
        if (quad == 0) {
            ml[slot * 128 + q] = l0;
            ml[slot * 128 + q + 16] = l1;
        }
    }
}

// ============================================================================
// 5. rmsnorm_merge: rows s<512 read y (BF16); rows s>=512 combine split-K
//    partials (nch[bq] chunks, 2..4; Opart BF16, l fp32, accumulate fp32).
// ============================================================================
__global__ __launch_bounds__(256) void rmsnorm_merge(
    const u16* __restrict__ y, const u16* __restrict__ Opart,
    const float* __restrict__ ml, u16* __restrict__ yb) {
    __shared__ float red[4];
    const int row = blockIdx.x, tid = threadIdx.x;
    const int b = row >> 11, s = row & 2047;
    float4 v;
    if (s < 512) {
        s16x4 pv = *(const s16x4*)(y + (size_t)row * 1024 + tid * 4);
        v.x = bf2f((u16)pv[0]); v.y = bf2f((u16)pv[1]);
        v.z = bf2f((u16)pv[2]); v.w = bf2f((u16)pv[3]);
    } else {
        const int nch_t[16] = {1,1,1,1,2,2,2,2,3,3,3,3,4,4,4,4};
        const int cst_t[16] = {0,1,2,3,4,6,8,10,12,15,18,21,24,28,32,36};
        const int bq = s >> 7, q = s & 127;
        const int e = tid * 4, h = e >> 6, dh = e & 63;
        const int n = nch_t[bq];
        const int slot0 = (b * 16 + h) * 36 + (cst_t[bq] - 4);
        float l = 0.f;
        f32x4 xa = {0.f, 0.f, 0.f, 0.f};
        const u16* P = Opart + (size_t)slot0 * 8192 + q * 64 + dh;
        for (int c = 0; c < n; ++c) {
            l += ml[(size_t)(slot0 + c) * 128 + q];
            s16x4 pv = *(const s16x4*)(P + (size_t)c * 8192);
            f32x4 pf = {bf2f((u16)pv[0]), bf2f((u16)pv[1]),
                        bf2f((u16)pv[2]), bf2f((u16)pv[3])};
            xa += pf;
        }
        float inv = 1.0f / l;
        v.x = xa[0] * inv; v.y = xa[1] * inv; v.z = xa[2] * inv; v.w = xa[3] * inv;
    }
    float ss = v.x * v.x + v.y * v.y + v.z * v.z + v.w * v.w;
    #pragma unroll
    for (int m = 1; m < 64; m <<= 1) ss += __shfl_xor(ss, m);
    if ((tid & 63) == 0) red[tid >> 6] = ss;
    __syncthreads();
    float tot = red[0] + red[1] + red[2] + red[3];
    float rn = 1.0f / sqrtf(tot * (1.0f / 1024.0f) + 1.1920929e-7f);
    u16 o[4] = {f2bf(v.x * rn), f2bf(v.y * rn), f2bf(v.z * rn), f2bf(v.w * rn)};
    *(uint2*)(yb + (size_t)row * 1024 + tid * 4) = *(const uint2*)o;
}

// ============================================================================
// launch — workspace (peak ~51 MB; ws is 256 MiB per harness poison-fill):
//   [0,      2.10M)  wproj_b  (prep -> gemm2)
//   [2.10M, 10.49M)  xb (prep -> gemm_qkv); then y BF16 @2.10M..10.49M
//                    (attn -> rms; xb dead by attn time)
//   [10.49M,13.63M)  wqkv_b (prep -> gemm_qkv)
//   [18.87M,27.26M)  Qb (gemm_qkv -> attn); then yb (rms -> gemm2)
//   [27.26M,29.36M)  Kb   [29.36M,31.46M) Vt
//   [31.46M,50.33M)  Opart (attn -> rms; 32 hb x 36 slots x 8192 BF16)
//   [50.33M,50.92M)  ml (1152 slots x 128 f32)
// ============================================================================
extern "C" void kernel_launch(void* const* d_in, const int* in_sizes, int n_in,
                              void* d_out, int out_size, void* d_ws, size_t ws_size,
                              hipStream_t stream) {
    const float* x      = (const float*)d_in[0];
    const float* w_qkv  = (const float*)d_in[1];
    const float* w_proj = (const float*)d_in[2];
    const float* q_gain = (const float*)d_in[3];
    float* out = (float*)d_out;
    char* ws = (char*)d_ws;

    u16*   wproj_b = (u16*)(ws);
    u16*   xb      = (u16*)(ws + 2097152);
    u16*   y       = (u16*)(ws + 2097152);
    u16*   wqkv_b  = (u16*)(ws + 10485760);
    u16*   Qb      = (u16*)(ws + 18874368);
    u16*   yb      = (u16*)(ws + 18874368);
    u16*   Kb      = (u16*)(ws + 27262976);
    u16*   Vt      = (u16*)(ws + 29360128);
    u16*   Opart   = (u16*)(ws + 31457280);
    float* mlb     = (float*)(ws + 50331648);

    prep<<<3328, 256, 0, stream>>>(w_qkv, w_proj, x, wqkv_b, wproj_b, xb);
    gemm_qkv<<<dim3(24, 32), 256, 0, stream>>>(xb, wqkv_b, q_gain, Qb, Kb, Vt);
    attn<<<dim3(32, 40), 256, 0, stream>>>(Qb, Kb, Vt, q_gain, y, Opart, mlb);
    rmsnorm_merge<<<4096, 256, 0, stream>>>(y, Opart, mlb, yb);
    gemm_bt<<<dim3(16, 32), 256, 0, stream>>>(yb, wproj_b, out, 4096, 1024, 1024);
}

// Round 16
// 165.092 us; speedup vs baseline: 1.0540x; 1.0160x over previous
//
#include <hip/hip_runtime.h>
#include <cstdint>

typedef unsigned short u16;
typedef __bf16 bf16x8 __attribute__((ext_vector_type(8)));
typedef __bf16 bf16x2 __attribute__((ext_vector_type(2)));
typedef short s16x4 __attribute__((ext_vector_type(4)));
typedef int s32x2 __attribute__((ext_vector_type(2)));
typedef float f32x4 __attribute__((ext_vector_type(4)));

// ---- bf16 helpers (RTNE, matching XLA/ml_dtypes) ----
__device__ __forceinline__ u16 f2bf(float f) {
    unsigned u = __float_as_uint(f);
    u = (u + 0x7fffu + ((u >> 16) & 1u)) >> 16;
    return (u16)u;
}
__device__ __forceinline__ float bf2f(u16 h) {
    return __uint_as_float(((unsigned)h) << 16);
}

// async global->LDS, 16B per lane; LDS dest = wave-uniform base + lane*16
__device__ __forceinline__ void glds16(const u16* g, u16* l) {
    __builtin_amdgcn_global_load_lds(
        (const __attribute__((address_space(1))) void*)g,
        (__attribute__((address_space(3))) void*)l, 16, 0, 0);
}

// pack 4 floats -> 4 bf16 via native casts (gfx950: v_cvt_pk_bf16_f32, RTNE)
__device__ __forceinline__ s16x4 pack_bf4(float p0, float p1, float p2, float p3) {
    bf16x2 lo = {(__bf16)p0, (__bf16)p1};
    bf16x2 hi = {(__bf16)p2, (__bf16)p3};
    s32x2 pk = {__builtin_bit_cast(int, lo), __builtin_bit_cast(int, hi)};
    return __builtin_bit_cast(s16x4, pk);
}

#if __has_builtin(__builtin_amdgcn_mfma_f32_16x16x16bf16_1k)
#define MFMA16(a, b, c) __builtin_amdgcn_mfma_f32_16x16x16bf16_1k(a, b, c, 0, 0, 0)
#else
static __device__ __forceinline__ f32x4 mfma16_asm(s16x4 a, s16x4 b, f32x4 c) {
    asm("v_mfma_f32_16x16x16_bf16 %0, %1, %2, %0" : "+v"(c) : "v"(a), "v"(b));
    return c;
}
#define MFMA16(a, b, c) mfma16_asm(a, b, c)
#endif

// ============================================================================
// 1. prep: ternary-quantize both weights (8 elems/lane) + cast x to bf16.
//    GRID = 1280 quant + 2048 cast = 3328.
// ============================================================================
__global__ __launch_bounds__(256) void prep(
    const float* __restrict__ w_qkv, const float* __restrict__ w_proj,
    const float* __restrict__ x,
    u16* __restrict__ wqkv_b, u16* __restrict__ wproj_b, u16* __restrict__ xb) {
    int bid = blockIdx.x;
    if (bid < 1280) {
        const float* w; u16* o; size_t base;
        if (bid < 768) { w = w_qkv; o = wqkv_b; base = (size_t)bid * 2048; }
        else { w = w_proj; o = wproj_b; base = (size_t)(bid - 768) * 2048; }
        size_t i = base + (size_t)threadIdx.x * 8;
        float4 A = *(const float4*)(w + i);
        float4 B = *(const float4*)(w + i + 4);
        float wf[8] = {A.x, A.y, A.z, A.w, B.x, B.y, B.z, B.w};
        float wbf[8], ab[8];
        #pragma unroll
        for (int e = 0; e < 8; ++e) { wbf[e] = bf2f(f2bf(wf[e])); ab[e] = fabsf(wbf[e]); }
        float s = ((ab[0] + ab[1]) + (ab[2] + ab[3])) + ((ab[4] + ab[5]) + (ab[6] + ab[7]));
        s += __shfl_xor(s, 1);
        s += __shfl_xor(s, 2);
        s += __shfl_xor(s, 4);   // 8-lane cluster = one 64-elem group
        float scale = bf2f(f2bf(s * (1.0f / 64.0f)));
        if (scale < 1e-8f) scale = 1e-8f;
        u16 ov[8];
        #pragma unroll
        for (int e = 0; e < 8; ++e) {
            float t = bf2f(f2bf(wbf[e] / scale));
            float q = rintf(t);
            q = fminf(1.0f, fmaxf(-1.0f, q));
            float d = bf2f(f2bf(q * scale - wbf[e]));
            ov[e] = f2bf(wbf[e] + d);
        }
        *(int4*)(o + i) = *(const int4*)ov;
    } else {
        size_t i = ((size_t)(bid - 1280) * 256 + threadIdx.x) * 8;
        float4 a = *(const float4*)(x + i);
        float4 b = *(const float4*)(x + i + 4);
        u16 o[8] = {f2bf(a.x), f2bf(a.y), f2bf(a.z), f2bf(a.w),
                    f2bf(b.x), f2bf(b.y), f2bf(b.z), f2bf(b.w)};
        *(int4*)(xb + i) = *(const int4*)o;
    }
}

// ============================================================================
// 2. gemm_qkv: xb[4096x1024] @ wqkv^T with FUSED RMSNorm+RoPE+gain epilogue.
//    Tile 128M x 64N, grid 24x32 = 768 blocks = 3/CU. BK=64 (R14).
//    NEW (R16): XCD-AWARE REMAP — physical block p round-robins XCDs as
//    p%8; assign each XCD 4 CONTIGUOUS A-panels (by = 4*(p%8) + (p/8)/24,
//    bx = (p/8)%24, bijective since 768%8==0). Measured R15: FETCH 34.5MB
//    vs 11MB unique input — each 128-row A panel was re-fetched by up to
//    8 non-coherent per-XCD L2s. Now each panel lives in exactly one L2;
//    B (3MB) fits a 4MB XCD L2 whole.
// ============================================================================
__global__ __launch_bounds__(256) void gemm_qkv(
    const u16* __restrict__ A, const u16* __restrict__ B,
    const float* __restrict__ gain,
    u16* __restrict__ Qb, u16* __restrict__ Kb, u16* __restrict__ Vt) {
    __shared__ u16 As[2 * 8192];   // 2 bufs x (2 sub x 128x32)
    __shared__ u16 Bs[2 * 4096];   // 2 bufs x (2 sub x 64x32)
    const int tid = threadIdx.x;
    const int lane = tid & 63, w = tid >> 6;
    const int quad = lane >> 4, l16 = lane & 15;
    const int p = blockIdx.y * 24 + blockIdx.x;   // physical linear id
    const int xcd = p & 7, j = p >> 3;            // j 0..95
    const int by = 4 * xcd + j / 24;              // 4 panels per XCD
    const int bx = j % 24;
    const int n0 = bx * 64, t0 = by * 128;
    const bool vblk = bx >= 20;
    const int K = 1024, nk = 16;   // 16 K-steps of 64
    const int b = by >> 4;           // batch (128-row tiles; 16 per batch)

    const int sra = w * 16 + (lane >> 2);   // A local row, +i*64
    const int srb = tid >> 2;               // B local row (0..63)
    const int sg4 = lane & 3;
    const int adst = (w * 16) * 32 + lane * 8;   // + i*64*32, + sub*4096
    const int bdst = w * 512 + lane * 8;         // + sub*2048

    f32x4 acc[2][4];
    f32x4 zero = {0.f, 0.f, 0.f, 0.f};
    #pragma unroll
    for (int i = 0; i < 2; ++i)
        #pragma unroll
        for (int jj = 0; jj < 4; ++jj) acc[i][jj] = zero;

    int aoff[2], boff[4];
    #pragma unroll
    for (int mi = 0; mi < 2; ++mi) {
        int r = w * 32 + mi * 16 + l16;
        aoff[mi] = r * 32 + (quad ^ ((r >> 1) & 3)) * 8;
    }
    #pragma unroll
    for (int ni = 0; ni < 4; ++ni) {
        int rb = ni * 16 + l16;
        boff[ni] = rb * 32 + (quad ^ ((rb >> 1) & 3)) * 8;
    }

    // stage K-step 0 (both subs) into buf 0
    #pragma unroll
    for (int sub = 0; sub < 2; ++sub) {
        #pragma unroll
        for (int i = 0; i < 2; ++i) {
            int r = sra + i * 64;
            int g = sg4 ^ ((r >> 1) & 3);
            glds16(A + (size_t)(t0 + r) * K + sub * 32 + g * 8,
                   As + sub * 4096 + adst + i * 2048);
        }
        int g = sg4 ^ ((srb >> 1) & 3);
        glds16(B + (size_t)(n0 + srb) * K + sub * 32 + g * 8,
               Bs + sub * 2048 + bdst);
    }
    __syncthreads();

    for (int kt = 0; kt < nk; ++kt) {
        if (kt + 1 < nk) {
            int k0 = (kt + 1) * 64, bi = (kt + 1) & 1;
            #pragma unroll
            for (int sub = 0; sub < 2; ++sub) {
                #pragma unroll
                for (int i = 0; i < 2; ++i) {
                    int r = sra + i * 64;
                    int g = sg4 ^ ((r >> 1) & 3);
                    glds16(A + (size_t)(t0 + r) * K + k0 + sub * 32 + g * 8,
                           As + bi * 8192 + sub * 4096 + adst + i * 2048);
                }
                int g = sg4 ^ ((srb >> 1) & 3);
                glds16(B + (size_t)(n0 + srb) * K + k0 + sub * 32 + g * 8,
                       Bs + bi * 4096 + sub * 2048 + bdst);
            }
        }
        #pragma unroll
        for (int sub = 0; sub < 2; ++sub) {
            const u16* as = As + (kt & 1) * 8192 + sub * 4096;
            const u16* bs = Bs + (kt & 1) * 4096 + sub * 2048;
            bf16x8 af[2], bfr[4];
            #pragma unroll
            for (int mi = 0; mi < 2; ++mi) af[mi]  = *(const bf16x8*)(as + aoff[mi]);
            #pragma unroll
            for (int ni = 0; ni < 4; ++ni) bfr[ni] = *(const bf16x8*)(bs + boff[ni]);
            if (!vblk) {
                #pragma unroll
                for (int mi = 0; mi < 2; ++mi)
                    #pragma unroll
                    for (int ni = 0; ni < 4; ++ni)
                        acc[mi][ni] = __builtin_amdgcn_mfma_f32_16x16x32_bf16(af[mi], bfr[ni], acc[mi][ni], 0, 0, 0);
            } else {
                #pragma unroll
                for (int mi = 0; mi < 2; ++mi)
                    #pragma unroll
                    for (int ni = 0; ni < 4; ++ni)
                        acc[mi][ni] = __builtin_amdgcn_mfma_f32_16x16x32_bf16(bfr[ni], af[mi], acc[mi][ni], 0, 0, 0);
            }
        }
        __syncthreads();
    }

    if (vblk) {
        const int kv = bx - 20;
        u16* vbase = Vt + (size_t)(b * 4 + kv) * 64 * 2048;
        const int si = (t0 + w * 32 + l16) & 2047;
        #pragma unroll
        for (int mi = 0; mi < 2; ++mi)
            #pragma unroll
            for (int ni = 0; ni < 4; ++ni) {
                int d = ni * 16 + quad * 4;
                #pragma unroll
                for (int r = 0; r < 4; ++r)
                    vbase[(size_t)(d + r) * 2048 + si + mi * 16] = f2bf(acc[mi][ni][r]);
            }
    } else {
        const bool isQ = bx < 16;
        const float sc = 0.18033688011112042f;
        const float g = isQ ? gain[bx] * sc : 1.0f;
        u16* base = isQ ? (Qb + (size_t)(b * 16 + bx) * 2048 * 64)
                        : (Kb + (size_t)(b * 4 + (bx - 16)) * 2048 * 64);
        const float eps = 1.1920929e-7f;
        const float invf0 = (float)(1.0 / pow(10000.0, (double)l16 / 32.0));
        const float invf1 = (float)(1.0 / pow(10000.0, (double)(l16 + 16) / 32.0));
        #pragma unroll
        for (int mi = 0; mi < 2; ++mi) {
            #pragma unroll
            for (int r = 0; r < 4; ++r) {
                float v0 = acc[mi][0][r], v1 = acc[mi][1][r];
                float v2 = acc[mi][2][r], v3 = acc[mi][3][r];
                float ssq = (v0 * v0 + v1 * v1) + (v2 * v2 + v3 * v3);
                #pragma unroll
                for (int m = 1; m < 16; m <<= 1) ssq += __shfl_xor(ssq, m);
                float rn = 1.0f / sqrtf(ssq * (1.0f / 64.0f) + eps);
                int si = (t0 + w * 32 + mi * 16 + quad * 4 + r) & 2047;
                float a0 = (float)si * invf0, a1 = (float)si * invf1;
                float c0 = __cosf(a0), s0 = __sinf(a0);
                float c1 = __cosf(a1), s1 = __sinf(a1);
                float x1a = v0 * rn, x2a = v2 * rn;
                float x1b = v1 * rn, x2b = v3 * rn;
                u16* row = base + (size_t)si * 64;
                row[l16]      = f2bf((x1a * c0 + x2a * s0) * g);
                row[l16 + 32] = f2bf((x2a * c0 - x1a * s0) * g);
                row[l16 + 16] = f2bf((x1b * c1 + x2b * s1) * g);
                row[l16 + 48] = f2bf((x2b * c1 - x1b * s1) * g);
            }
        }
    }
}

// ============================================================================
// 3. GEMM (proj): C[M,N] fp32 = A[M,K]bf16 @ B[N,K]^T. 128M x 64N, BK=64
//    (R15). NEW (R16): same XCD-aware remap as gemm_qkv (512%8==0;
//    by = 4*(p%8) + (p/8)/16, bx = (p/8)%16). LDS 48KB.
// ============================================================================
__global__ __launch_bounds__(256) void gemm_bt(
    const u16* __restrict__ A, const u16* __restrict__ B,
    float* __restrict__ C, int M, int N, int K) {
    __shared__ u16 As[2 * 8192];
    __shared__ u16 Bs[2 * 4096];
    const int tid = threadIdx.x;
    const int lane = tid & 63, w = tid >> 6;
    const int quad = lane >> 4, l16 = lane & 15;
    const int p = blockIdx.y * 16 + blockIdx.x;   // physical linear id
    const int xcd = p & 7, j = p >> 3;            // j 0..63
    const int by = 4 * xcd + j / 16;
    const int bx = j % 16;
    const int m0 = by * 128, n0 = bx * 64;
    const int wm = (w >> 1) * 64, wn = (w & 1) * 32;

    const int sra = w * 16 + (lane >> 2);
    const int srb = tid >> 2;
    const int sg4 = lane & 3;
    const int adst = (w * 16) * 32 + lane * 8;
    const int bdst = w * 512 + lane * 8;

    f32x4 acc[4][2];
    f32x4 zero = {0.f, 0.f, 0.f, 0.f};
    #pragma unroll
    for (int i = 0; i < 4; ++i) { acc[i][0] = zero; acc[i][1] = zero; }

    int aoff[4], boff[2];
    #pragma unroll
    for (int mi = 0; mi < 4; ++mi) {
        int r = wm + mi * 16 + l16;
        aoff[mi] = r * 32 + (quad ^ ((r >> 1) & 3)) * 8;
    }
    #pragma unroll
    for (int ni = 0; ni < 2; ++ni) {
        int r = wn + ni * 16 + l16;
        boff[ni] = r * 32 + (quad ^ ((r >> 1) & 3)) * 8;
    }

    const int nk = K >> 6;   // 64-col K-steps
    #pragma unroll
    for (int sub = 0; sub < 2; ++sub) {
        #pragma unroll
        for (int i = 0; i < 2; ++i) {
            int r = sra + i * 64;
            int g = sg4 ^ ((r >> 1) & 3);
            glds16(A + (size_t)(m0 + r) * K + sub * 32 + g * 8,
                   As + sub * 4096 + adst + i * 2048);
        }
        int g = sg4 ^ ((srb >> 1) & 3);
        glds16(B + (size_t)(n0 + srb) * K + sub * 32 + g * 8,
               Bs + sub * 2048 + bdst);
    }
    __syncthreads();

    for (int kt = 0; kt < nk; ++kt) {
        if (kt + 1 < nk) {
            int k0 = (kt + 1) * 64, bi = (kt + 1) & 1;
            #pragma unroll
            for (int sub = 0; sub < 2; ++sub) {
                #pragma unroll
                for (int i = 0; i < 2; ++i) {
                    int r = sra + i * 64;
                    int g = sg4 ^ ((r >> 1) & 3);
                    glds16(A + (size_t)(m0 + r) * K + k0 + sub * 32 + g * 8,
                           As + bi * 8192 + sub * 4096 + adst + i * 2048);
                }
                int g = sg4 ^ ((srb >> 1) & 3);
                glds16(B + (size_t)(n0 + srb) * K + k0 + sub * 32 + g * 8,
                       Bs + bi * 4096 + sub * 2048 + bdst);
            }
        }
        #pragma unroll
        for (int sub = 0; sub < 2; ++sub) {
            const u16* as = As + (kt & 1) * 8192 + sub * 4096;
            const u16* bs = Bs + (kt & 1) * 4096 + sub * 2048;
            bf16x8 af[4], bfr[2];
            #pragma unroll
            for (int mi = 0; mi < 4; ++mi) af[mi]  = *(const bf16x8*)(as + aoff[mi]);
            #pragma unroll
            for (int ni = 0; ni < 2; ++ni) bfr[ni] = *(const bf16x8*)(bs + boff[ni]);
            #pragma unroll
            for (int mi = 0; mi < 4; ++mi)
                #pragma unroll
                for (int ni = 0; ni < 2; ++ni)
                    acc[mi][ni] = __builtin_amdgcn_mfma_f32_16x16x32_bf16(af[mi], bfr[ni], acc[mi][ni], 0, 0, 0);
        }
        __syncthreads();
    }
    #pragma unroll
    for (int mi = 0; mi < 4; ++mi)
        #pragma unroll
        for (int ni = 0; ni < 2; ++ni) {
            int rg = m0 + wm + mi * 16 + quad * 4;
            int cg = n0 + wn + ni * 16 + l16;
            float* cp = C + (size_t)rg * N + cg;
            #pragma unroll
            for (int r = 0; r < 4; ++r) cp[(size_t)r * N] = acc[mi][ni][r];
        }
}

// ============================================================================
// 4. Flash attention (R9 structure — verified best; attn ~44us).
//    256 thr / 4 waves; each wave owns 32 Q-rows (two 16-bands), K/V LDS
//    fragments feed both bands. Q-tile 128, KV tile 64, dbuf LDS 32KB.
//    Grid 32 x 40 LPT chunks (1..8 tiles), Opart bf16, y bf16.
//    launch_bounds (256,4): kernel needs ~60 VGPR; any tighter cap (R11's
//    ",5" -> 48 VGPR) or extra live state (R8's PV pipeline) spills to
//    scratch and regresses 1.3-1.8x. Do not tighten.
// ============================================================================
__global__ __launch_bounds__(256, 4) void attn(
    const u16* __restrict__ Qb, const u16* __restrict__ Kb,
    const u16* __restrict__ Vt, const float* __restrict__ gain,
    u16* __restrict__ y, u16* __restrict__ Opart, float* __restrict__ ml) {
    __shared__ u16 Ks[2][4096];
    __shared__ u16 Vs[2][4096];
    const int hb = blockIdx.x;
    const int h = hb & 15, b = hb >> 4, kvh = h >> 2;
    const int yid = 39 - blockIdx.y;   // LPT: physical y=0 -> biggest chunk
    // chunk tables: bq (0..15), T=2bq+2 tiles, nch=ceil(T/8)
    const int nch_t[16] = {1,1,1,1,2,2,2,2,3,3,3,3,4,4,4,4};
    const int cst_t[16] = {0,1,2,3,4,6,8,10,12,15,18,21,24,28,32,36};
    int bq = 0;
    #pragma unroll
    for (int i = 1; i < 16; ++i) if (yid >= cst_t[i]) bq = i;
    const int nc = nch_t[bq], ch = yid - cst_t[bq];
    const int T = 2 * bq + 2;
    const int c0 = ch * T / nc;
    const int nj = (ch + 1) * T / nc - c0;
    const bool partial = nc > 1;
    const int q0 = bq * 128;

    const int tid = threadIdx.x, lane = tid & 63, w = tid >> 6;  // w 0..3
    const int quad = lane >> 4, l16 = lane & 15;
    const float nM = -(12.0f * fabsf(gain[h]) + 1.0f);
    const f32x4 minit = {nM, nM, nM, nM};

    const u16* Qg = Qb + ((size_t)(b * 16 + h) * 2048 + q0) * 64;
    const u16* Kg = Kb + (size_t)(b * 4 + kvh) * 2048 * 64;
    const u16* Vg = Vt + (size_t)(b * 4 + kvh) * 64 * 2048;

    // two bands per wave: q rows w*32+l16 and +16
    const int qr0 = w * 32 + l16;
    const bf16x8 qa00 = *(const bf16x8*)(Qg + (size_t)qr0 * 64 + quad * 8);
    const bf16x8 qa01 = *(const bf16x8*)(Qg + (size_t)qr0 * 64 + 32 + quad * 8);
    const bf16x8 qa10 = *(const bf16x8*)(Qg + (size_t)(qr0 + 16) * 64 + quad * 8);
    const bf16x8 qa11 = *(const bf16x8*)(Qg + (size_t)(qr0 + 16) * 64 + 32 + quad * 8);

    // staging: 256 thr x 16B x 2 passes per 8KB tile
    const int sr = tid >> 3;                 // 0..31
    const int sg = (tid & 7) ^ (sr & 7);     // XOR swizzle (same for sr+32)
    const int so = tid * 8;                  // u16 offset in LDS

    {
        int c = (c0 + nj - 1) * 64, bi = (nj - 1) & 1;
        glds16(Kg + (size_t)(c + sr) * 64 + sg * 8,        &Ks[bi][0] + so);
        glds16(Kg + (size_t)(c + sr + 32) * 64 + sg * 8,   &Ks[bi][0] + so + 2048);
        glds16(Vg + (size_t)sr * 2048 + c + sg * 8,        &Vs[bi][0] + so);
        glds16(Vg + (size_t)(sr + 32) * 2048 + c + sg * 8, &Vs[bi][0] + so + 2048);
    }
    __syncthreads();

    f32x4 o0[4], o1[4];
    f32x4 zero = {0.f, 0.f, 0.f, 0.f};
    #pragma unroll
    for (int t = 0; t < 4; ++t) { o0[t] = zero; o1[t] = zero; }
    float l0 = 0.f, l1 = 0.f;

    for (int jj = nj - 1; jj >= 0; --jj) {
        if (jj > 0) {
            int c = (c0 + jj - 1) * 64, bi = (jj - 1) & 1;
            glds16(Kg + (size_t)(c + sr) * 64 + sg * 8,        &Ks[bi][0] + so);
            glds16(Kg + (size_t)(c + sr + 32) * 64 + sg * 8,   &Ks[bi][0] + so + 2048);
            glds16(Vg + (size_t)sr * 2048 + c + sg * 8,        &Vs[bi][0] + so);
            glds16(Vg + (size_t)(sr + 32) * 2048 + c + sg * 8, &Vs[bi][0] + so + 2048);
        }
        const u16* Kt = &Ks[jj & 1][0];
        const u16* Vl = &Vs[jj & 1][0];
        const int jg = c0 + jj;
        const int d0 = 8 * bq + 2 * w - 4 * jg;   // band0 position (16-units)
        const int d1 = d0 + 1;
        if (d1 >= 0) {
            const int tm0 = d0 < 3 ? d0 : 3;       // may be -1 (band0 idle)
            const int tm1 = d1 < 3 ? d1 : 3;
            s16x4 pf0[4], pf1[4];
            float rs0 = 0.f, rs1 = 0.f;
            __builtin_amdgcn_s_setprio(1);
            #pragma unroll
            for (int t = 0; t < 4; ++t) {
                if (t <= tm1) {
                    int rk = t * 16 + l16;
                    bf16x8 kb0 = *(const bf16x8*)(Kt + rk * 64 + ((quad ^ (rk & 7)) * 8));
                    bf16x8 kb1 = *(const bf16x8*)(Kt + rk * 64 + (((quad + 4) ^ (rk & 7)) * 8));
                    if (t <= tm0) {
                        f32x4 s = __builtin_amdgcn_mfma_f32_16x16x32_bf16(kb0, qa00, minit, 0, 0, 0);
                        s = __builtin_amdgcn_mfma_f32_16x16x32_bf16(kb1, qa01, s, 0, 0, 0);
                        if (t == d0) {
                            #pragma unroll
                            for (int r = 0; r < 4; ++r)
                                if (quad * 4 + r > l16) s[r] = -1e30f;
                        }
                        float p0 = __builtin_amdgcn_exp2f(s[0]);
                        float p1 = __builtin_amdgcn_exp2f(s[1]);
                        float p2 = __builtin_amdgcn_exp2f(s[2]);
                        float p3 = __builtin_amdgcn_exp2f(s[3]);
                        rs0 += (p0 + p1) + (p2 + p3);
                        pf0[t] = pack_bf4(p0, p1, p2, p3);
                    }
                    {
                        f32x4 s = __builtin_amdgcn_mfma_f32_16x16x32_bf16(kb0, qa10, minit, 0, 0, 0);
                        s = __builtin_amdgcn_mfma_f32_16x16x32_bf16(kb1, qa11, s, 0, 0, 0);
                        if (t == d1) {
                            #pragma unroll
                            for (int r = 0; r < 4; ++r)
                                if (quad * 4 + r > l16) s[r] = -1e30f;
                        }
                        float p0 = __builtin_amdgcn_exp2f(s[0]);
                        float p1 = __builtin_amdgcn_exp2f(s[1]);
                        float p2 = __builtin_amdgcn_exp2f(s[2]);
                        float p3 = __builtin_amdgcn_exp2f(s[3]);
                        rs1 += (p0 + p1) + (p2 + p3);
                        pf1[t] = pack_bf4(p0, p1, p2, p3);
                    }
                }
            }
            l0 += rs0; l1 += rs1;
            #pragma unroll
            for (int dt = 0; dt < 4; ++dt) {
                int rv = dt * 16 + l16;
                #pragma unroll
                for (int kt = 0; kt < 4; ++kt) {
                    if (kt <= tm1) {
                        int gv = 2 * kt + (quad >> 1);
                        s16x4 va = *(const s16x4*)(Vl + rv * 64 + ((gv ^ (rv & 7)) * 8) + (quad & 1) * 4);
                        if (kt <= tm0) o0[dt] = MFMA16(va, pf0[kt], o0[dt]);
                        o1[dt] = MFMA16(va, pf1[kt], o1[dt]);
                    }
                }
            }
            __builtin_amdgcn_s_setprio(0);
        }
        __syncthreads();
    }

    // finish row-sums: quads hold disjoint k-slices
    l0 += __shfl_xor(l0, 16);
    l0 += __shfl_xor(l0, 32);
    l1 += __shfl_xor(l1, 16);
    l1 += __shfl_xor(l1, 32);

    const int q = w * 32 + l16;
    if (!partial) {
        const float inv0 = 1.0f / l0, inv1 = 1.0f / l1;
        const size_t row0 = (size_t)b * 2048 + q0 + q;
        u16* yp0 = y + row0 * 1024 + h * 64 + quad * 4;
        u16* yp1 = y + (row0 + 16) * 1024 + h * 64 + quad * 4;
        #pragma unroll
        for (int dt = 0; dt < 4; ++dt) {
            f32x4 a = o0[dt] * inv0;
            *(s16x4*)(yp0 + dt * 16) = pack_bf4(a[0], a[1], a[2], a[3]);
            f32x4 c = o1[dt] * inv1;
            *(s16x4*)(yp1 + dt * 16) = pack_bf4(c[0], c[1], c[2], c[3]);
        }
    } else {
        const int slot = hb * 36 + (yid - 4);
        u16* Op = Opart + (size_t)slot * 8192;
        #pragma unroll
        for (int dt = 0; dt < 4; ++dt) {
            *(s16x4*)(Op + q * 64 + dt * 16 + quad * 4) =
                pack_bf4(o0[dt][0], o0[dt][1], o0[dt][2], o0[dt][3]);
            *(s16x4*)(Op + (q + 16) * 64 + dt * 16 + quad * 4) =
                pack_bf4(o1[dt][0], o1[dt][1], o1[dt][2], o1[dt][3]);
        }
        if (quad == 0) {
            ml[slot * 128 + q] = l0;
            ml[slot * 128 + q + 16] = l1;
        }
    }
}

// ============================================================================
// 5. rmsnorm_merge: rows s<512 read y (BF16); rows s>=512 combine split-K
//    partials (nch[bq] chunks, 2..4; Opart BF16, l fp32, accumulate fp32).
// ============================================================================
__global__ __launch_bounds__(256) void rmsnorm_merge(
    const u16* __restrict__ y, const u16* __restrict__ Opart,
    const float* __restrict__ ml, u16* __restrict__ yb) {
    __shared__ float red[4];
    const int row = blockIdx.x, tid = threadIdx.x;
    const int b = row >> 11, s = row & 2047;
    float4 v;
    if (s < 512) {
        s16x4 pv = *(const s16x4*)(y + (size_t)row * 1024 + tid * 4);
        v.x = bf2f((u16)pv[0]); v.y = bf2f((u16)pv[1]);
        v.z = bf2f((u16)pv[2]); v.w = bf2f((u16)pv[3]);
    } else {
        const int nch_t[16] = {1,1,1,1,2,2,2,2,3,3,3,3,4,4,4,4};
        const int cst_t[16] = {0,1,2,3,4,6,8,10,12,15,18,21,24,28,32,36};
        const int bq = s >> 7, q = s & 127;
        const int e = tid * 4, h = e >> 6, dh = e & 63;
        const int n = nch_t[bq];
        const int slot0 = (b * 16 + h) * 36 + (cst_t[bq] - 4);
        float l = 0.f;
        f32x4 xa = {0.f, 0.f, 0.f, 0.f};
        const u16* P = Opart + (size_t)slot0 * 8192 + q * 64 + dh;
        for (int c = 0; c < n; ++c) {
            l += ml[(size_t)(slot0 + c) * 128 + q];
            s16x4 pv = *(const s16x4*)(P + (size_t)c * 8192);
            f32x4 pf = {bf2f((u16)pv[0]), bf2f((u16)pv[1]),
                        bf2f((u16)pv[2]), bf2f((u16)pv[3])};
            xa += pf;
        }
        float inv = 1.0f / l;
        v.x = xa[0] * inv; v.y = xa[1] * inv; v.z = xa[2] * inv; v.w = xa[3] * inv;
    }
    float ss = v.x * v.x + v.y * v.y + v.z * v.z + v.w * v.w;
    #pragma unroll
    for (int m = 1; m < 64; m <<= 1) ss += __shfl_xor(ss, m);
    if ((tid & 63) == 0) red[tid >> 6] = ss;
    __syncthreads();
    float tot = red[0] + red[1] + red[2] + red[3];
    float rn = 1.0f / sqrtf(tot * (1.0f / 1024.0f) + 1.1920929e-7f);
    u16 o[4] = {f2bf(v.x * rn), f2bf(v.y * rn), f2bf(v.z * rn), f2bf(v.w * rn)};
    *(uint2*)(yb + (size_t)row * 1024 + tid * 4) = *(const uint2*)o;
}

// ============================================================================
// launch — workspace (peak ~51 MB; ws is 256 MiB per harness poison-fill):
//   [0,      2.10M)  wproj_b  (prep -> gemm2)
//   [2.10M, 10.49M)  xb (prep -> gemm_qkv); then y BF16 @2.10M..10.49M
//                    (attn -> rms; xb dead by attn time)
//   [10.49M,13.63M)  wqkv_b (prep -> gemm_qkv)
//   [18.87M,27.26M)  Qb (gemm_qkv -> attn); then yb (rms -> gemm2)
//   [27.26M,29.36M)  Kb   [29.36M,31.46M) Vt
//   [31.46M,50.33M)  Opart (attn -> rms; 32 hb x 36 slots x 8192 BF16)
//   [50.33M,50.92M)  ml (1152 slots x 128 f32)
// ============================================================================
extern "C" void kernel_launch(void* const* d_in, const int* in_sizes, int n_in,
                              void* d_out, int out_size, void* d_ws, size_t ws_size,
                              hipStream_t stream) {
    const float* x      = (const float*)d_in[0];
    const float* w_qkv  = (const float*)d_in[1];
    const float* w_proj = (const float*)d_in[2];
    const float* q_gain = (const float*)d_in[3];
    float* out = (float*)d_out;
    char* ws = (char*)d_ws;

    u16*   wproj_b = (u16*)(ws);
    u16*   xb      = (u16*)(ws + 2097152);
    u16*   y       = (u16*)(ws + 2097152);
    u16*   wqkv_b  = (u16*)(ws + 10485760);
    u16*   Qb      = (u16*)(ws + 18874368);
    u16*   yb      = (u16*)(ws + 18874368);
    u16*   Kb      = (u16*)(ws + 27262976);
    u16*   Vt      = (u16*)(ws + 29360128);
    u16*   Opart   = (u16*)(ws + 31457280);
    float* mlb     = (float*)(ws + 50331648);

    prep<<<3328, 256, 0, stream>>>(w_qkv, w_proj, x, wqkv_b, wproj_b, xb);
    gemm_qkv<<<dim3(24, 32), 256, 0, stream>>>(xb, wqkv_b, q_gain, Qb, Kb, Vt);
    attn<<<dim3(32, 40), 256, 0, stream>>>(Qb, Kb, Vt, q_gain, y, Opart, mlb);
    rmsnorm_merge<<<4096, 256, 0, stream>>>(y, Opart, mlb, yb);
    gemm_bt<<<dim3(16, 32), 256, 0, stream>>>(yb, wproj_b, out, 4096, 1024, 1024);
}

// Round 17
// 164.782 us; speedup vs baseline: 1.0559x; 1.0019x over previous
//
#include <hip/hip_runtime.h>
#include <cstdint>

typedef unsigned short u16;
typedef __bf16 bf16x8 __attribute__((ext_vector_type(8)));
typedef __bf16 bf16x2 __attribute__((ext_vector_type(2)));
typedef short s16x4 __attribute__((ext_vector_type(4)));
typedef int s32x2 __attribute__((ext_vector_type(2)));
typedef float f32x4 __attribute__((ext_vector_type(4)));

// ---- bf16 helpers (RTNE, matching XLA/ml_dtypes) ----
__device__ __forceinline__ u16 f2bf(float f) {
    unsigned u = __float_as_uint(f);
    u = (u + 0x7fffu + ((u >> 16) & 1u)) >> 16;
    return (u16)u;
}
__device__ __forceinline__ float bf2f(u16 h) {
    return __uint_as_float(((unsigned)h) << 16);
}

// async global->LDS, 16B per lane; LDS dest = wave-uniform base + lane*16
__device__ __forceinline__ void glds16(const u16* g, u16* l) {
    __builtin_amdgcn_global_load_lds(
        (const __attribute__((address_space(1))) void*)g,
        (__attribute__((address_space(3))) void*)l, 16, 0, 0);
}

// pack 4 floats -> 4 bf16 via native casts (gfx950: v_cvt_pk_bf16_f32, RTNE)
__device__ __forceinline__ s16x4 pack_bf4(float p0, float p1, float p2, float p3) {
    bf16x2 lo = {(__bf16)p0, (__bf16)p1};
    bf16x2 hi = {(__bf16)p2, (__bf16)p3};
    s32x2 pk = {__builtin_bit_cast(int, lo), __builtin_bit_cast(int, hi)};
    return __builtin_bit_cast(s16x4, pk);
}

#if __has_builtin(__builtin_amdgcn_mfma_f32_16x16x16bf16_1k)
#define MFMA16(a, b, c) __builtin_amdgcn_mfma_f32_16x16x16bf16_1k(a, b, c, 0, 0, 0)
#else
static __device__ __forceinline__ f32x4 mfma16_asm(s16x4 a, s16x4 b, f32x4 c) {
    asm("v_mfma_f32_16x16x16_bf16 %0, %1, %2, %0" : "+v"(c) : "v"(a), "v"(b));
    return c;
}
#define MFMA16(a, b, c) mfma16_asm(a, b, c)
#endif

// ============================================================================
// 1. prep: ternary-quantize both weights (8 elems/lane) + cast x to bf16.
//    GRID = 1280 quant + 2048 cast = 3328.
// ============================================================================
__global__ __launch_bounds__(256) void prep(
    const float* __restrict__ w_qkv, const float* __restrict__ w_proj,
    const float* __restrict__ x,
    u16* __restrict__ wqkv_b, u16* __restrict__ wproj_b, u16* __restrict__ xb) {
    int bid = blockIdx.x;
    if (bid < 1280) {
        const float* w; u16* o; size_t base;
        if (bid < 768) { w = w_qkv; o = wqkv_b; base = (size_t)bid * 2048; }
        else { w = w_proj; o = wproj_b; base = (size_t)(bid - 768) * 2048; }
        size_t i = base + (size_t)threadIdx.x * 8;
        float4 A = *(const float4*)(w + i);
        float4 B = *(const float4*)(w + i + 4);
        float wf[8] = {A.x, A.y, A.z, A.w, B.x, B.y, B.z, B.w};
        float wbf[8], ab[8];
        #pragma unroll
        for (int e = 0; e < 8; ++e) { wbf[e] = bf2f(f2bf(wf[e])); ab[e] = fabsf(wbf[e]); }
        float s = ((ab[0] + ab[1]) + (ab[2] + ab[3])) + ((ab[4] + ab[5]) + (ab[6] + ab[7]));
        s += __shfl_xor(s, 1);
        s += __shfl_xor(s, 2);
        s += __shfl_xor(s, 4);   // 8-lane cluster = one 64-elem group
        float scale = bf2f(f2bf(s * (1.0f / 64.0f)));
        if (scale < 1e-8f) scale = 1e-8f;
        u16 ov[8];
        #pragma unroll
        for (int e = 0; e < 8; ++e) {
            float t = bf2f(f2bf(wbf[e] / scale));
            float q = rintf(t);
            q = fminf(1.0f, fmaxf(-1.0f, q));
            float d = bf2f(f2bf(q * scale - wbf[e]));
            ov[e] = f2bf(wbf[e] + d);
        }
        *(int4*)(o + i) = *(const int4*)ov;
    } else {
        size_t i = ((size_t)(bid - 1280) * 256 + threadIdx.x) * 8;
        float4 a = *(const float4*)(x + i);
        float4 b = *(const float4*)(x + i + 4);
        u16 o[8] = {f2bf(a.x), f2bf(a.y), f2bf(a.z), f2bf(a.w),
                    f2bf(b.x), f2bf(b.y), f2bf(b.z), f2bf(b.w)};
        *(int4*)(xb + i) = *(const int4*)o;
    }
}

// ============================================================================
// 2. gemm_qkv: xb[4096x1024] @ wqkv^T with FUSED RMSNorm+RoPE+gain epilogue.
//    Tile 128M x 64N, grid 24x32 = 768 blocks = 3/CU. BK=64 (R14) +
//    XCD-aware remap (R16: each XCD owns 4 contiguous A-panels; FETCH
//    34.5MB -> near-unique). LDS 48KB.
// ============================================================================
__global__ __launch_bounds__(256) void gemm_qkv(
    const u16* __restrict__ A, const u16* __restrict__ B,
    const float* __restrict__ gain,
    u16* __restrict__ Qb, u16* __restrict__ Kb, u16* __restrict__ Vt) {
    __shared__ u16 As[2 * 8192];   // 2 bufs x (2 sub x 128x32)
    __shared__ u16 Bs[2 * 4096];   // 2 bufs x (2 sub x 64x32)
    const int tid = threadIdx.x;
    const int lane = tid & 63, w = tid >> 6;
    const int quad = lane >> 4, l16 = lane & 15;
    const int p = blockIdx.y * 24 + blockIdx.x;   // physical linear id
    const int xcd = p & 7, j = p >> 3;            // j 0..95
    const int by = 4 * xcd + j / 24;              // 4 panels per XCD
    const int bx = j % 24;
    const int n0 = bx * 64, t0 = by * 128;
    const bool vblk = bx >= 20;
    const int K = 1024, nk = 16;   // 16 K-steps of 64
    const int b = by >> 4;           // batch (128-row tiles; 16 per batch)

    const int sra = w * 16 + (lane >> 2);   // A local row, +i*64
    const int srb = tid >> 2;               // B local row (0..63)
    const int sg4 = lane & 3;
    const int adst = (w * 16) * 32 + lane * 8;   // + i*64*32, + sub*4096
    const int bdst = w * 512 + lane * 8;         // + sub*2048

    f32x4 acc[2][4];
    f32x4 zero = {0.f, 0.f, 0.f, 0.f};
    #pragma unroll
    for (int i = 0; i < 2; ++i)
        #pragma unroll
        for (int jj = 0; jj < 4; ++jj) acc[i][jj] = zero;

    int aoff[2], boff[4];
    #pragma unroll
    for (int mi = 0; mi < 2; ++mi) {
        int r = w * 32 + mi * 16 + l16;
        aoff[mi] = r * 32 + (quad ^ ((r >> 1) & 3)) * 8;
    }
    #pragma unroll
    for (int ni = 0; ni < 4; ++ni) {
        int rb = ni * 16 + l16;
        boff[ni] = rb * 32 + (quad ^ ((rb >> 1) & 3)) * 8;
    }

    // stage K-step 0 (both subs) into buf 0
    #pragma unroll
    for (int sub = 0; sub < 2; ++sub) {
        #pragma unroll
        for (int i = 0; i < 2; ++i) {
            int r = sra + i * 64;
            int g = sg4 ^ ((r >> 1) & 3);
            glds16(A + (size_t)(t0 + r) * K + sub * 32 + g * 8,
                   As + sub * 4096 + adst + i * 2048);
        }
        int g = sg4 ^ ((srb >> 1) & 3);
        glds16(B + (size_t)(n0 + srb) * K + sub * 32 + g * 8,
               Bs + sub * 2048 + bdst);
    }
    __syncthreads();

    for (int kt = 0; kt < nk; ++kt) {
        if (kt + 1 < nk) {
            int k0 = (kt + 1) * 64, bi = (kt + 1) & 1;
            #pragma unroll
            for (int sub = 0; sub < 2; ++sub) {
                #pragma unroll
                for (int i = 0; i < 2; ++i) {
                    int r = sra + i * 64;
                    int g = sg4 ^ ((r >> 1) & 3);
                    glds16(A + (size_t)(t0 + r) * K + k0 + sub * 32 + g * 8,
                           As + bi * 8192 + sub * 4096 + adst + i * 2048);
                }
                int g = sg4 ^ ((srb >> 1) & 3);
                glds16(B + (size_t)(n0 + srb) * K + k0 + sub * 32 + g * 8,
                       Bs + bi * 4096 + sub * 2048 + bdst);
            }
        }
        #pragma unroll
        for (int sub = 0; sub < 2; ++sub) {
            const u16* as = As + (kt & 1) * 8192 + sub * 4096;
            const u16* bs = Bs + (kt & 1) * 4096 + sub * 2048;
            bf16x8 af[2], bfr[4];
            #pragma unroll
            for (int mi = 0; mi < 2; ++mi) af[mi]  = *(const bf16x8*)(as + aoff[mi]);
            #pragma unroll
            for (int ni = 0; ni < 4; ++ni) bfr[ni] = *(const bf16x8*)(bs + boff[ni]);
            if (!vblk) {
                #pragma unroll
                for (int mi = 0; mi < 2; ++mi)
                    #pragma unroll
                    for (int ni = 0; ni < 4; ++ni)
                        acc[mi][ni] = __builtin_amdgcn_mfma_f32_16x16x32_bf16(af[mi], bfr[ni], acc[mi][ni], 0, 0, 0);
            } else {
                #pragma unroll
                for (int mi = 0; mi < 2; ++mi)
                    #pragma unroll
                    for (int ni = 0; ni < 4; ++ni)
                        acc[mi][ni] = __builtin_amdgcn_mfma_f32_16x16x32_bf16(bfr[ni], af[mi], acc[mi][ni], 0, 0, 0);
            }
        }
        __syncthreads();
    }

    if (vblk) {
        const int kv = bx - 20;
        u16* vbase = Vt + (size_t)(b * 4 + kv) * 64 * 2048;
        const int si = (t0 + w * 32 + l16) & 2047;
        #pragma unroll
        for (int mi = 0; mi < 2; ++mi)
            #pragma unroll
            for (int ni = 0; ni < 4; ++ni) {
                int d = ni * 16 + quad * 4;
                #pragma unroll
                for (int r = 0; r < 4; ++r)
                    vbase[(size_t)(d + r) * 2048 + si + mi * 16] = f2bf(acc[mi][ni][r]);
            }
    } else {
        const bool isQ = bx < 16;
        const float sc = 0.18033688011112042f;
        const float g = isQ ? gain[bx] * sc : 1.0f;
        u16* base = isQ ? (Qb + (size_t)(b * 16 + bx) * 2048 * 64)
                        : (Kb + (size_t)(b * 4 + (bx - 16)) * 2048 * 64);
        const float eps = 1.1920929e-7f;
        const float invf0 = (float)(1.0 / pow(10000.0, (double)l16 / 32.0));
        const float invf1 = (float)(1.0 / pow(10000.0, (double)(l16 + 16) / 32.0));
        #pragma unroll
        for (int mi = 0; mi < 2; ++mi) {
            #pragma unroll
            for (int r = 0; r < 4; ++r) {
                float v0 = acc[mi][0][r], v1 = acc[mi][1][r];
                float v2 = acc[mi][2][r], v3 = acc[mi][3][r];
                float ssq = (v0 * v0 + v1 * v1) + (v2 * v2 + v3 * v3);
                #pragma unroll
                for (int m = 1; m < 16; m <<= 1) ssq += __shfl_xor(ssq, m);
                float rn = 1.0f / sqrtf(ssq * (1.0f / 64.0f) + eps);
                int si = (t0 + w * 32 + mi * 16 + quad * 4 + r) & 2047;
                float a0 = (float)si * invf0, a1 = (float)si * invf1;
                float c0 = __cosf(a0), s0 = __sinf(a0);
                float c1 = __cosf(a1), s1 = __sinf(a1);
                float x1a = v0 * rn, x2a = v2 * rn;
                float x1b = v1 * rn, x2b = v3 * rn;
                u16* row = base + (size_t)si * 64;
                row[l16]      = f2bf((x1a * c0 + x2a * s0) * g);
                row[l16 + 32] = f2bf((x2a * c0 - x1a * s0) * g);
                row[l16 + 16] = f2bf((x1b * c1 + x2b * s1) * g);
                row[l16 + 48] = f2bf((x2b * c1 - x1b * s1) * g);
            }
        }
    }
}

// ============================================================================
// 3. GEMM (proj): C[M,N] fp32 = A[M,K]bf16 @ B[N,K]^T. 128M x 64N, BK=64
//    (R15) + XCD-aware remap (R16). LDS 48KB.
// ============================================================================
__global__ __launch_bounds__(256) void gemm_bt(
    const u16* __restrict__ A, const u16* __restrict__ B,
    float* __restrict__ C, int M, int N, int K) {
    __shared__ u16 As[2 * 8192];
    __shared__ u16 Bs[2 * 4096];
    const int tid = threadIdx.x;
    const int lane = tid & 63, w = tid >> 6;
    const int quad = lane >> 4, l16 = lane & 15;
    const int p = blockIdx.y * 16 + blockIdx.x;   // physical linear id
    const int xcd = p & 7, j = p >> 3;            // j 0..63
    const int by = 4 * xcd + j / 16;
    const int bx = j % 16;
    const int m0 = by * 128, n0 = bx * 64;
    const int wm = (w >> 1) * 64, wn = (w & 1) * 32;

    const int sra = w * 16 + (lane >> 2);
    const int srb = tid >> 2;
    const int sg4 = lane & 3;
    const int adst = (w * 16) * 32 + lane * 8;
    const int bdst = w * 512 + lane * 8;

    f32x4 acc[4][2];
    f32x4 zero = {0.f, 0.f, 0.f, 0.f};
    #pragma unroll
    for (int i = 0; i < 4; ++i) { acc[i][0] = zero; acc[i][1] = zero; }

    int aoff[4], boff[2];
    #pragma unroll
    for (int mi = 0; mi < 4; ++mi) {
        int r = wm + mi * 16 + l16;
        aoff[mi] = r * 32 + (quad ^ ((r >> 1) & 3)) * 8;
    }
    #pragma unroll
    for (int ni = 0; ni < 2; ++ni) {
        int r = wn + ni * 16 + l16;
        boff[ni] = r * 32 + (quad ^ ((r >> 1) & 3)) * 8;
    }

    const int nk = K >> 6;   // 64-col K-steps
    #pragma unroll
    for (int sub = 0; sub < 2; ++sub) {
        #pragma unroll
        for (int i = 0; i < 2; ++i) {
            int r = sra + i * 64;
            int g = sg4 ^ ((r >> 1) & 3);
            glds16(A + (size_t)(m0 + r) * K + sub * 32 + g * 8,
                   As + sub * 4096 + adst + i * 2048);
        }
        int g = sg4 ^ ((srb >> 1) & 3);
        glds16(B + (size_t)(n0 + srb) * K + sub * 32 + g * 8,
               Bs + sub * 2048 + bdst);
    }
    __syncthreads();

    for (int kt = 0; kt < nk; ++kt) {
        if (kt + 1 < nk) {
            int k0 = (kt + 1) * 64, bi = (kt + 1) & 1;
            #pragma unroll
            for (int sub = 0; sub < 2; ++sub) {
                #pragma unroll
                for (int i = 0; i < 2; ++i) {
                    int r = sra + i * 64;
                    int g = sg4 ^ ((r >> 1) & 3);
                    glds16(A + (size_t)(m0 + r) * K + k0 + sub * 32 + g * 8,
                           As + bi * 8192 + sub * 4096 + adst + i * 2048);
                }
                int g = sg4 ^ ((srb >> 1) & 3);
                glds16(B + (size_t)(n0 + srb) * K + k0 + sub * 32 + g * 8,
                       Bs + bi * 4096 + sub * 2048 + bdst);
            }
        }
        #pragma unroll
        for (int sub = 0; sub < 2; ++sub) {
            const u16* as = As + (kt & 1) * 8192 + sub * 4096;
            const u16* bs = Bs + (kt & 1) * 4096 + sub * 2048;
            bf16x8 af[4], bfr[2];
            #pragma unroll
            for (int mi = 0; mi < 4; ++mi) af[mi]  = *(const bf16x8*)(as + aoff[mi]);
            #pragma unroll
            for (int ni = 0; ni < 2; ++ni) bfr[ni] = *(const bf16x8*)(bs + boff[ni]);
            #pragma unroll
            for (int mi = 0; mi < 4; ++mi)
                #pragma unroll
                for (int ni = 0; ni < 2; ++ni)
                    acc[mi][ni] = __builtin_amdgcn_mfma_f32_16x16x32_bf16(af[mi], bfr[ni], acc[mi][ni], 0, 0, 0);
        }
        __syncthreads();
    }
    #pragma unroll
    for (int mi = 0; mi < 4; ++mi)
        #pragma unroll
        for (int ni = 0; ni < 2; ++ni) {
            int rg = m0 + wm + mi * 16 + quad * 4;
            int cg = n0 + wn + ni * 16 + l16;
            float* cp = C + (size_t)rg * N + cg;
            #pragma unroll
            for (int r = 0; r < 4; ++r) cp[(size_t)r * N] = acc[mi][ni][r];
        }
}

// ============================================================================
// 4. Flash attention (R9 structure — verified best; attn ~42us).
//    256 thr / 4 waves; each wave owns 32 Q-rows (two 16-bands), K/V LDS
//    fragments feed both bands. Q-tile 128, KV tile 64, dbuf LDS 32KB.
//    NEW (R17): COARSER split-K — chunks up to 12 KV-tiles, nch=ceil(T/12)
//    -> 30 chunks/hb, grid 32x30 = 960 blocks = 3.75/CU LPT; partial slots
//    36 -> 24/hb, Opart 18.9 -> 12.6MB bf16 (saves ~6MB write + ~6MB read).
//    hb -> XCD mapping is already ideal (p%8 = hb%8 since gridDim.x=32).
//    launch_bounds (256,4): kernel needs ~60 VGPR; tighter caps spill.
// ============================================================================
__global__ __launch_bounds__(256, 4) void attn(
    const u16* __restrict__ Qb, const u16* __restrict__ Kb,
    const u16* __restrict__ Vt, const float* __restrict__ gain,
    u16* __restrict__ y, u16* __restrict__ Opart, float* __restrict__ ml) {
    __shared__ u16 Ks[2][4096];
    __shared__ u16 Vs[2][4096];
    const int hb = blockIdx.x;
    const int h = hb & 15, b = hb >> 4, kvh = h >> 2;
    const int yid = 29 - blockIdx.y;   // LPT: physical y=0 -> biggest chunk
    // chunk tables: bq (0..15), T=2bq+2 tiles, nch=ceil(T/12)
    const int nch_t[16] = {1,1,1,1,1,1,2,2,2,2,2,2,3,3,3,3};
    const int cst_t[16] = {0,1,2,3,4,5,6,8,10,12,14,16,18,21,24,27};
    int bq = 0;
    #pragma unroll
    for (int i = 1; i < 16; ++i) if (yid >= cst_t[i]) bq = i;
    const int nc = nch_t[bq], ch = yid - cst_t[bq];
    const int T = 2 * bq + 2;
    const int c0 = ch * T / nc;
    const int nj = (ch + 1) * T / nc - c0;
    const bool partial = nc > 1;
    const int q0 = bq * 128;

    const int tid = threadIdx.x, lane = tid & 63, w = tid >> 6;  // w 0..3
    const int quad = lane >> 4, l16 = lane & 15;
    const float nM = -(12.0f * fabsf(gain[h]) + 1.0f);
    const f32x4 minit = {nM, nM, nM, nM};

    const u16* Qg = Qb + ((size_t)(b * 16 + h) * 2048 + q0) * 64;
    const u16* Kg = Kb + (size_t)(b * 4 + kvh) * 2048 * 64;
    const u16* Vg = Vt + (size_t)(b * 4 + kvh) * 64 * 2048;

    // two bands per wave: q rows w*32+l16 and +16
    const int qr0 = w * 32 + l16;
    const bf16x8 qa00 = *(const bf16x8*)(Qg + (size_t)qr0 * 64 + quad * 8);
    const bf16x8 qa01 = *(const bf16x8*)(Qg + (size_t)qr0 * 64 + 32 + quad * 8);
    const bf16x8 qa10 = *(const bf16x8*)(Qg + (size_t)(qr0 + 16) * 64 + quad * 8);
    const bf16x8 qa11 = *(const bf16x8*)(Qg + (size_t)(qr0 + 16) * 64 + 32 + quad * 8);

    // staging: 256 thr x 16B x 2 passes per 8KB tile
    const int sr = tid >> 3;                 // 0..31
    const int sg = (tid & 7) ^ (sr & 7);     // XOR swizzle (same for sr+32)
    const int so = tid * 8;                  // u16 offset in LDS

    {
        int c = (c0 + nj - 1) * 64, bi = (nj - 1) & 1;
        glds16(Kg + (size_t)(c + sr) * 64 + sg * 8,        &Ks[bi][0] + so);
        glds16(Kg + (size_t)(c + sr + 32) * 64 + sg * 8,   &Ks[bi][0] + so + 2048);
        glds16(Vg + (size_t)sr * 2048 + c + sg * 8,        &Vs[bi][0] + so);
        glds16(Vg + (size_t)(sr + 32) * 2048 + c + sg * 8, &Vs[bi][0] + so + 2048);
    }
    __syncthreads();

    f32x4 o0[4], o1[4];
    f32x4 zero = {0.f, 0.f, 0.f, 0.f};
    #pragma unroll
    for (int t = 0; t < 4; ++t) { o0[t] = zero; o1[t] = zero; }
    float l0 = 0.f, l1 = 0.f;

    for (int jj = nj - 1; jj >= 0; --jj) {
        if (jj > 0) {
            int c = (c0 + jj - 1) * 64, bi = (jj - 1) & 1;
            glds16(Kg + (size_t)(c + sr) * 64 + sg * 8,        &Ks[bi][0] + so);
            glds16(Kg + (size_t)(c + sr + 32) * 64 + sg * 8,   &Ks[bi][0] + so + 2048);
            glds16(Vg + (size_t)sr * 2048 + c + sg * 8,        &Vs[bi][0] + so);
            glds16(Vg + (size_t)(sr + 32) * 2048 + c + sg * 8, &Vs[bi][0] + so + 2048);
        }
        const u16* Kt = &Ks[jj & 1][0];
        const u16* Vl = &Vs[jj & 1][0];
        const int jg = c0 + jj;
        const int d0 = 8 * bq + 2 * w - 4 * jg;   // band0 position (16-units)
        const int d1 = d0 + 1;
        if (d1 >= 0) {
            const int tm0 = d0 < 3 ? d0 : 3;       // may be -1 (band0 idle)
            const int tm1 = d1 < 3 ? d1 : 3;
            s16x4 pf0[4], pf1[4];
            float rs0 = 0.f, rs1 = 0.f;
            __builtin_amdgcn_s_setprio(1);
            #pragma unroll
            for (int t = 0; t < 4; ++t) {
                if (t <= tm1) {
                    int rk = t * 16 + l16;
                    bf16x8 kb0 = *(const bf16x8*)(Kt + rk * 64 + ((quad ^ (rk & 7)) * 8));
                    bf16x8 kb1 = *(const bf16x8*)(Kt + rk * 64 + (((quad + 4) ^ (rk & 7)) * 8));
                    if (t <= tm0) {
                        f32x4 s = __builtin_amdgcn_mfma_f32_16x16x32_bf16(kb0, qa00, minit, 0, 0, 0);
                        s = __builtin_amdgcn_mfma_f32_16x16x32_bf16(kb1, qa01, s, 0, 0, 0);
                        if (t == d0) {
                            #pragma unroll
                            for (int r = 0; r < 4; ++r)
                                if (quad * 4 + r > l16) s[r] = -1e30f;
                        }
                        float p0 = __builtin_amdgcn_exp2f(s[0]);
                        float p1 = __builtin_amdgcn_exp2f(s[1]);
                        float p2 = __builtin_amdgcn_exp2f(s[2]);
                        float p3 = __builtin_amdgcn_exp2f(s[3]);
                        rs0 += (p0 + p1) + (p2 + p3);
                        pf0[t] = pack_bf4(p0, p1, p2, p3);
                    }
                    {
                        f32x4 s = __builtin_amdgcn_mfma_f32_16x16x32_bf16(kb0, qa10, minit, 0, 0, 0);
                        s = __builtin_amdgcn_mfma_f32_16x16x32_bf16(kb1, qa11, s, 0, 0, 0);
                        if (t == d1) {
                            #pragma unroll
                            for (int r = 0; r < 4; ++r)
                                if (quad * 4 + r > l16) s[r] = -1e30f;
                        }
                        float p0 = __builtin_amdgcn_exp2f(s[0]);
                        float p1 = __builtin_amdgcn_exp2f(s[1]);
                        float p2 = __builtin_amdgcn_exp2f(s[2]);
                        float p3 = __builtin_amdgcn_exp2f(s[3]);
                        rs1 += (p0 + p1) + (p2 + p3);
                        pf1[t] = pack_bf4(p0, p1, p2, p3);
                    }
                }
            }
            l0 += rs0; l1 += rs1;
            #pragma unroll
            for (int dt = 0; dt < 4; ++dt) {
                int rv = dt * 16 + l16;
                #pragma unroll
                for (int kt = 0; kt < 4; ++kt) {
                    if (kt <= tm1) {
                        int gv = 2 * kt + (quad >> 1);
                        s16x4 va = *(const s16x4*)(Vl + rv * 64 + ((gv ^ (rv & 7)) * 8) + (quad & 1) * 4);
                        if (kt <= tm0) o0[dt] = MFMA16(va, pf0[kt], o0[dt]);
                        o1[dt] = MFMA16(va, pf1[kt], o1[dt]);
                    }
                }
            }
            __builtin_amdgcn_s_setprio(0);
        }
        __syncthreads();
    }

    // finish row-sums: quads hold disjoint k-slices
    l0 += __shfl_xor(l0, 16);
    l0 += __shfl_xor(l0, 32);
    l1 += __shfl_xor(l1, 16);
    l1 += __shfl_xor(l1, 32);

    const int q = w * 32 + l16;
    if (!partial) {
        const float inv0 = 1.0f / l0, inv1 = 1.0f / l1;
        const size_t row0 = (size_t)b * 2048 + q0 + q;
        u16* yp0 = y + row0 * 1024 + h * 64 + quad * 4;
        u16* yp1 = y + (row0 + 16) * 1024 + h * 64 + quad * 4;
        #pragma unroll
        for (int dt = 0; dt < 4; ++dt) {
            f32x4 a = o0[dt] * inv0;
            *(s16x4*)(yp0 + dt * 16) = pack_bf4(a[0], a[1], a[2], a[3]);
            f32x4 c = o1[dt] * inv1;
            *(s16x4*)(yp1 + dt * 16) = pack_bf4(c[0], c[1], c[2], c[3]);
        }
    } else {
        const int slot = hb * 24 + (yid - 6);
        u16* Op = Opart + (size_t)slot * 8192;
        #pragma unroll
        for (int dt = 0; dt < 4; ++dt) {
            *(s16x4*)(Op + q * 64 + dt * 16 + quad * 4) =
                pack_bf4(o0[dt][0], o0[dt][1], o0[dt][2], o0[dt][3]);
            *(s16x4*)(Op + (q + 16) * 64 + dt * 16 + quad * 4) =
                pack_bf4(o1[dt][0], o1[dt][1], o1[dt][2], o1[dt][3]);
        }
        if (quad == 0) {
            ml[slot * 128 + q] = l0;
            ml[slot * 128 + q + 16] = l1;
        }
    }
}

// ============================================================================
// 5. rmsnorm_merge: rows s<768 read y (BF16); rows s>=768 combine split-K
//    partials (nch[bq] chunks, 2..3; Opart BF16, l fp32, accumulate fp32).
// ============================================================================
__global__ __launch_bounds__(256) void rmsnorm_merge(
    const u16* __restrict__ y, const u16* __restrict__ Opart,
    const float* __restrict__ ml, u16* __restrict__ yb) {
    __shared__ float red[4];
    const int row = blockIdx.x, tid = threadIdx.x;
    const int b = row >> 11, s = row & 2047;
    float4 v;
    if (s < 768) {
        s16x4 pv = *(const s16x4*)(y + (size_t)row * 1024 + tid * 4);
        v.x = bf2f((u16)pv[0]); v.y = bf2f((u16)pv[1]);
        v.z = bf2f((u16)pv[2]); v.w = bf2f((u16)pv[3]);
    } else {
        const int nch_t[16] = {1,1,1,1,1,1,2,2,2,2,2,2,3,3,3,3};
        const int cst_t[16] = {0,1,2,3,4,5,6,8,10,12,14,16,18,21,24,27};
        const int bq = s >> 7, q = s & 127;
        const int e = tid * 4, h = e >> 6, dh = e & 63;
        const int n = nch_t[bq];
        const int slot0 = (b * 16 + h) * 24 + (cst_t[bq] - 6);
        float l = 0.f;
        f32x4 xa = {0.f, 0.f, 0.f, 0.f};
        const u16* P = Opart + (size_t)slot0 * 8192 + q * 64 + dh;
        for (int c = 0; c < n; ++c) {
            l += ml[(size_t)(slot0 + c) * 128 + q];
            s16x4 pv = *(const s16x4*)(P + (size_t)c * 8192);
            f32x4 pf = {bf2f((u16)pv[0]), bf2f((u16)pv[1]),
                        bf2f((u16)pv[2]), bf2f((u16)pv[3])};
            xa += pf;
        }
        float inv = 1.0f / l;
        v.x = xa[0] * inv; v.y = xa[1] * inv; v.z = xa[2] * inv; v.w = xa[3] * inv;
    }
    float ss = v.x * v.x + v.y * v.y + v.z * v.z + v.w * v.w;
    #pragma unroll
    for (int m = 1; m < 64; m <<= 1) ss += __shfl_xor(ss, m);
    if ((tid & 63) == 0) red[tid >> 6] = ss;
    __syncthreads();
    float tot = red[0] + red[1] + red[2] + red[3];
    float rn = 1.0f / sqrtf(tot * (1.0f / 1024.0f) + 1.1920929e-7f);
    u16 o[4] = {f2bf(v.x * rn), f2bf(v.y * rn), f2bf(v.z * rn), f2bf(v.w * rn)};
    *(uint2*)(yb + (size_t)row * 1024 + tid * 4) = *(const uint2*)o;
}

// ============================================================================
// launch — workspace (peak ~44.4 MB; ws is 256 MiB per harness poison-fill):
//   [0,      2.10M)  wproj_b  (prep -> gemm2)
//   [2.10M, 10.49M)  xb (prep -> gemm_qkv); then y BF16 @2.10M..10.49M
//                    (attn -> rms; xb dead by attn time)
//   [10.49M,13.63M)  wqkv_b (prep -> gemm_qkv)
//   [18.87M,27.26M)  Qb (gemm_qkv -> attn); then yb (rms -> gemm2)
//   [27.26M,29.36M)  Kb   [29.36M,31.46M) Vt
//   [31.46M,44.04M)  Opart (attn -> rms; 32 hb x 24 slots x 8192 BF16)
//   [44.04M,44.43M)  ml (768 slots x 128 f32)
// ============================================================================
extern "C" void kernel_launch(void* const* d_in, const int* in_sizes, int n_in,
                              void* d_out, int out_size, void* d_ws, size_t ws_size,
                              hipStream_t stream) {
    const float* x      = (const float*)d_in[0];
    const float* w_qkv  = (const float*)d_in[1];
    const float* w_proj = (const float*)d_in[2];
    const float* q_gain = (const float*)d_in[3];
    float* out = (float*)d_out;
    char* ws = (char*)d_ws;

    u16*   wproj_b = (u16*)(ws);
    u16*   xb      = (u16*)(ws + 2097152);
    u16*   y       = (u16*)(ws + 2097152);
    u16*   wqkv_b  = (u16*)(ws + 10485760);
    u16*   Qb      = (u16*)(ws + 18874368);
    u16*   yb      = (u16*)(ws + 18874368);
    u16*   Kb      = (u16*)(ws + 27262976);
    u16*   Vt      = (u16*)(ws + 29360128);
    u16*   Opart   = (u16*)(ws + 31457280);
    float* mlb     = (float*)(ws + 44040192);

    prep<<<3328, 256, 0, stream>>>(w_qkv, w_proj, x, wqkv_b, wproj_b, xb);
    gemm_qkv<<<dim3(24, 32), 256, 0, stream>>>(xb, wqkv_b, q_gain, Qb, Kb, Vt);
    attn<<<dim3(32, 30), 256, 0, stream>>>(Qb, Kb, Vt, q_gain, y, Opart, mlb);
    rmsnorm_merge<<<4096, 256, 0, stream>>>(y, Opart, mlb, yb);
    gemm_bt<<<dim3(16, 32), 256, 0, stream>>>(yb, wproj_b, out, 4096, 1024, 1024);
}